// Round 1
// baseline (1692.201 us; speedup 1.0000x reference)
//
#include <hip/hip_runtime.h>
#include <math.h>

#define N_NODES 50000
#define N_EDGES 500000
// feature widths per layer
// L1: 128 -> 64, L2: 64 -> 128, L3: 128 -> 32

// ---------------- GEMM kernels: C[N,OUT] = X[N,IN] @ W[IN,OUT] ----------------
// W staged in LDS (<=32 KiB), one thread per output row (or row-half), K via float4.

__global__ __launch_bounds__(256) void gemm_128_64(const float* __restrict__ X,
                                                   const float* __restrict__ W,
                                                   float* __restrict__ C, int n) {
    __shared__ float Wl[128 * 64];
    for (int i = threadIdx.x; i < 128 * 64; i += 256) Wl[i] = W[i];
    __syncthreads();
    int row = blockIdx.x * 256 + threadIdx.x;
    if (row >= n) return;
    const float4* xr = (const float4*)(X + (long)row * 128);
    float acc[64];
#pragma unroll
    for (int j = 0; j < 64; j++) acc[j] = 0.f;
    for (int k4 = 0; k4 < 32; k4++) {
        float4 xv = xr[k4];
        const float* w0 = &Wl[(k4 * 4 + 0) * 64];
        const float* w1 = &Wl[(k4 * 4 + 1) * 64];
        const float* w2 = &Wl[(k4 * 4 + 2) * 64];
        const float* w3 = &Wl[(k4 * 4 + 3) * 64];
#pragma unroll
        for (int j = 0; j < 64; j++)
            acc[j] += xv.x * w0[j] + xv.y * w1[j] + xv.z * w2[j] + xv.w * w3[j];
    }
    float* cr = C + (long)row * 64;
#pragma unroll
    for (int j = 0; j < 64; j++) cr[j] = acc[j];
}

__global__ __launch_bounds__(256) void gemm_64_128(const float* __restrict__ X,
                                                   const float* __restrict__ W,
                                                   float* __restrict__ C, int n) {
    __shared__ float Wl[64 * 128];
    for (int i = threadIdx.x; i < 64 * 128; i += 256) Wl[i] = W[i];
    __syncthreads();
    int t = blockIdx.x * 256 + threadIdx.x;
    int row = t >> 1;
    int half = (t & 1) * 64;
    if (row >= n) return;
    const float4* xr = (const float4*)(X + (long)row * 64);
    float acc[64];
#pragma unroll
    for (int j = 0; j < 64; j++) acc[j] = 0.f;
    for (int k4 = 0; k4 < 16; k4++) {
        float4 xv = xr[k4];
        const float* w0 = &Wl[(k4 * 4 + 0) * 128 + half];
        const float* w1 = &Wl[(k4 * 4 + 1) * 128 + half];
        const float* w2 = &Wl[(k4 * 4 + 2) * 128 + half];
        const float* w3 = &Wl[(k4 * 4 + 3) * 128 + half];
#pragma unroll
        for (int j = 0; j < 64; j++)
            acc[j] += xv.x * w0[j] + xv.y * w1[j] + xv.z * w2[j] + xv.w * w3[j];
    }
    float* cr = C + (long)row * 128 + half;
#pragma unroll
    for (int j = 0; j < 64; j++) cr[j] = acc[j];
}

__global__ __launch_bounds__(256) void gemm_128_32(const float* __restrict__ X,
                                                   const float* __restrict__ W,
                                                   float* __restrict__ C, int n) {
    __shared__ float Wl[128 * 32];
    for (int i = threadIdx.x; i < 128 * 32; i += 256) Wl[i] = W[i];
    __syncthreads();
    int row = blockIdx.x * 256 + threadIdx.x;
    if (row >= n) return;
    const float4* xr = (const float4*)(X + (long)row * 128);
    float acc[32];
#pragma unroll
    for (int j = 0; j < 32; j++) acc[j] = 0.f;
    for (int k4 = 0; k4 < 32; k4++) {
        float4 xv = xr[k4];
        const float* w0 = &Wl[(k4 * 4 + 0) * 32];
        const float* w1 = &Wl[(k4 * 4 + 1) * 32];
        const float* w2 = &Wl[(k4 * 4 + 2) * 32];
        const float* w3 = &Wl[(k4 * 4 + 3) * 32];
#pragma unroll
        for (int j = 0; j < 32; j++)
            acc[j] += xv.x * w0[j] + xv.y * w1[j] + xv.z * w2[j] + xv.w * w3[j];
    }
    float* cr = C + (long)row * 32;
#pragma unroll
    for (int j = 0; j < 32; j++) cr[j] = acc[j];
}

// ---------------- agg init with bias folded in: agg[n*F + j] = b[j] ----------------
__global__ __launch_bounds__(256) void init_bias(float* __restrict__ agg,
                                                 const float* __restrict__ b,
                                                 int total, int fmask) {
    int i = blockIdx.x * 256 + threadIdx.x;
    if (i < total) agg[i] = b[i & fmask];
}

// ---------------- edge scatter: agg[dst] += sup[src] * w  (atomics) ----------------
template <int F>
__global__ __launch_bounds__(256) void scatter_edges(const float* __restrict__ sup,
                                                     const int* __restrict__ src,
                                                     const int* __restrict__ dst,
                                                     const float* __restrict__ w,
                                                     float* __restrict__ agg) {
    const int CH = F / 4;  // float4 chunks per edge
    int tid = blockIdx.x * 256 + threadIdx.x;
    int e = tid / CH;
    int c = tid - e * CH;
    if (e >= N_EDGES) return;
    int s = src[e];
    int d = dst[e];
    float wt = w[e];
    float4 v = ((const float4*)(sup + (long)s * F))[c];
    float* a = agg + (long)d * F + c * 4;
    atomicAdd(a + 0, v.x * wt);
    atomicAdd(a + 1, v.y * wt);
    atomicAdd(a + 2, v.z * wt);
    atomicAdd(a + 3, v.w * wt);
}

// ---------------- elementwise sigmoid (bias already in agg) ----------------
__global__ __launch_bounds__(256) void sigmoid_k(const float* __restrict__ agg,
                                                 float* __restrict__ h, int total) {
    int i = blockIdx.x * 256 + threadIdx.x;
    if (i < total) h[i] = 1.f / (1.f + expf(-agg[i]));
}

extern "C" void kernel_launch(void* const* d_in, const int* in_sizes, int n_in,
                              void* d_out, int out_size, void* d_ws, size_t ws_size,
                              hipStream_t stream) {
    const float* x  = (const float*)d_in[0];
    const int*   ei = (const int*)d_in[1];
    const float* ew = (const float*)d_in[2];
    const float* W1 = (const float*)d_in[3];
    const float* b1 = (const float*)d_in[4];
    const float* W2 = (const float*)d_in[5];
    const float* b2 = (const float*)d_in[6];
    const float* W3 = (const float*)d_in[7];
    const float* b3 = (const float*)d_in[8];

    const int* src = ei;            // edge_index[0]
    const int* dst = ei + N_EDGES;  // edge_index[1]

    float* out  = (float*)d_out;                       // [N,32]
    float* feat = out + (long)N_NODES * 32;            // [N,128] = h2

    float* ws0 = (float*)d_ws;            // support buffer, up to N*128
    float* ws1 = ws0 + (long)N_NODES * 128;  // agg buffer, up to N*128
    float* ws2 = ws1 + (long)N_NODES * 128;  // h1, N*64

    const int B = 256;

    // ---- Layer 1: 128 -> 64, sigmoid ----
    gemm_128_64<<<(N_NODES + B - 1) / B, B, 0, stream>>>(x, W1, ws0, N_NODES);
    init_bias<<<(N_NODES * 64 + B - 1) / B, B, 0, stream>>>(ws1, b1, N_NODES * 64, 63);
    scatter_edges<64><<<(N_EDGES * 16 + B - 1) / B, B, 0, stream>>>(ws0, src, dst, ew, ws1);
    sigmoid_k<<<(N_NODES * 64 + B - 1) / B, B, 0, stream>>>(ws1, ws2, N_NODES * 64);

    // ---- Layer 2: 64 -> 128, sigmoid -> feat (second output) ----
    gemm_64_128<<<(2 * N_NODES + B - 1) / B, B, 0, stream>>>(ws2, W2, ws0, N_NODES);
    init_bias<<<(N_NODES * 128 + B - 1) / B, B, 0, stream>>>(ws1, b2, N_NODES * 128, 127);
    scatter_edges<128><<<(N_EDGES * 32 + B - 1) / B, B, 0, stream>>>(ws0, src, dst, ew, ws1);
    sigmoid_k<<<(N_NODES * 128 + B - 1) / B, B, 0, stream>>>(ws1, feat, N_NODES * 128);

    // ---- Layer 3: 128 -> 32, no activation -> out (first output) ----
    gemm_128_32<<<(N_NODES + B - 1) / B, B, 0, stream>>>(feat, W3, ws0, N_NODES);
    init_bias<<<(N_NODES * 32 + B - 1) / B, B, 0, stream>>>(out, b3, N_NODES * 32, 31);
    scatter_edges<32><<<(N_EDGES * 8 + B - 1) / B, B, 0, stream>>>(ws0, src, dst, ew, out);
}

// Round 2
// 505.688 us; speedup vs baseline: 3.3463x; 3.3463x over previous
//
#include <hip/hip_runtime.h>
#include <math.h>

#define N_NODES 50000
#define N_EDGES 500000
// L1: 128 -> 64, L2: 64 -> 128, L3: 128 -> 32

// ---------------- GEMM kernels: C[N,OUT] = X[N,IN] @ W[IN,OUT] ----------------
__global__ __launch_bounds__(256) void gemm_128_64(const float* __restrict__ X,
                                                   const float* __restrict__ W,
                                                   float* __restrict__ C, int n) {
    __shared__ float Wl[128 * 64];
    for (int i = threadIdx.x; i < 128 * 64; i += 256) Wl[i] = W[i];
    __syncthreads();
    int row = blockIdx.x * 256 + threadIdx.x;
    if (row >= n) return;
    const float4* xr = (const float4*)(X + (long)row * 128);
    float acc[64];
#pragma unroll
    for (int j = 0; j < 64; j++) acc[j] = 0.f;
    for (int k4 = 0; k4 < 32; k4++) {
        float4 xv = xr[k4];
        const float* w0 = &Wl[(k4 * 4 + 0) * 64];
        const float* w1 = &Wl[(k4 * 4 + 1) * 64];
        const float* w2 = &Wl[(k4 * 4 + 2) * 64];
        const float* w3 = &Wl[(k4 * 4 + 3) * 64];
#pragma unroll
        for (int j = 0; j < 64; j++)
            acc[j] += xv.x * w0[j] + xv.y * w1[j] + xv.z * w2[j] + xv.w * w3[j];
    }
    float* cr = C + (long)row * 64;
#pragma unroll
    for (int j = 0; j < 64; j++) cr[j] = acc[j];
}

__global__ __launch_bounds__(256) void gemm_64_128(const float* __restrict__ X,
                                                   const float* __restrict__ W,
                                                   float* __restrict__ C, int n) {
    __shared__ float Wl[64 * 128];
    for (int i = threadIdx.x; i < 64 * 128; i += 256) Wl[i] = W[i];
    __syncthreads();
    int t = blockIdx.x * 256 + threadIdx.x;
    int row = t >> 1;
    int half = (t & 1) * 64;
    if (row >= n) return;
    const float4* xr = (const float4*)(X + (long)row * 64);
    float acc[64];
#pragma unroll
    for (int j = 0; j < 64; j++) acc[j] = 0.f;
    for (int k4 = 0; k4 < 16; k4++) {
        float4 xv = xr[k4];
        const float* w0 = &Wl[(k4 * 4 + 0) * 128 + half];
        const float* w1 = &Wl[(k4 * 4 + 1) * 128 + half];
        const float* w2 = &Wl[(k4 * 4 + 2) * 128 + half];
        const float* w3 = &Wl[(k4 * 4 + 3) * 128 + half];
#pragma unroll
        for (int j = 0; j < 64; j++)
            acc[j] += xv.x * w0[j] + xv.y * w1[j] + xv.z * w2[j] + xv.w * w3[j];
    }
    float* cr = C + (long)row * 128 + half;
#pragma unroll
    for (int j = 0; j < 64; j++) cr[j] = acc[j];
}

__global__ __launch_bounds__(256) void gemm_128_32(const float* __restrict__ X,
                                                   const float* __restrict__ W,
                                                   float* __restrict__ C, int n) {
    __shared__ float Wl[128 * 32];
    for (int i = threadIdx.x; i < 128 * 32; i += 256) Wl[i] = W[i];
    __syncthreads();
    int row = blockIdx.x * 256 + threadIdx.x;
    if (row >= n) return;
    const float4* xr = (const float4*)(X + (long)row * 128);
    float acc[32];
#pragma unroll
    for (int j = 0; j < 32; j++) acc[j] = 0.f;
    for (int k4 = 0; k4 < 32; k4++) {
        float4 xv = xr[k4];
        const float* w0 = &Wl[(k4 * 4 + 0) * 32];
        const float* w1 = &Wl[(k4 * 4 + 1) * 32];
        const float* w2 = &Wl[(k4 * 4 + 2) * 32];
        const float* w3 = &Wl[(k4 * 4 + 3) * 32];
#pragma unroll
        for (int j = 0; j < 32; j++)
            acc[j] += xv.x * w0[j] + xv.y * w1[j] + xv.z * w2[j] + xv.w * w3[j];
    }
    float* cr = C + (long)row * 32;
#pragma unroll
    for (int j = 0; j < 32; j++) cr[j] = acc[j];
}

// ---------------- CSR build (by dst), rebuilt every launch ----------------
__global__ __launch_bounds__(256) void zero_deg(int* __restrict__ deg) {
    int i = blockIdx.x * 256 + threadIdx.x;
    if (i < N_NODES) deg[i] = 0;
}

__global__ __launch_bounds__(256) void hist_k(const int* __restrict__ dst, int* __restrict__ deg) {
    int e = blockIdx.x * 256 + threadIdx.x;
    if (e < N_EDGES) atomicAdd(&deg[dst[e]], 1);
}

// single-block exclusive scan of deg -> row_ptr (and cursor copy)
__global__ __launch_bounds__(1024) void scan_k(const int* __restrict__ deg,
                                               int* __restrict__ row_ptr,
                                               int* __restrict__ cursor) {
    __shared__ int sums[1024];
    int t = threadIdx.x;
    const int CH = (N_NODES + 1023) / 1024;  // 49
    int start = t * CH;
    int s = 0;
    for (int i = 0; i < CH; i++) {
        int idx = start + i;
        if (idx < N_NODES) s += deg[idx];
    }
    sums[t] = s;
    __syncthreads();
    for (int off = 1; off < 1024; off <<= 1) {
        int v = (t >= off) ? sums[t - off] : 0;
        __syncthreads();
        sums[t] += v;
        __syncthreads();
    }
    int run = (t == 0) ? 0 : sums[t - 1];
    for (int i = 0; i < CH; i++) {
        int idx = start + i;
        if (idx < N_NODES) {
            row_ptr[idx] = run;
            cursor[idx] = run;
            run += deg[idx];
        }
    }
    if (t == 0) row_ptr[N_NODES] = sums[1023];
}

// scatter edges into CSR slots: csr[pos] = (src, weight)
__global__ __launch_bounds__(256) void reorder_k(const int* __restrict__ src,
                                                 const int* __restrict__ dst,
                                                 const float* __restrict__ w,
                                                 int* __restrict__ cursor,
                                                 int2* __restrict__ csr) {
    int e = blockIdx.x * 256 + threadIdx.x;
    if (e >= N_EDGES) return;
    int pos = atomicAdd(&cursor[dst[e]], 1);
    csr[pos] = make_int2(src[e], __float_as_int(w[e]));
}

// ---------------- gather aggregation (no atomics), bias+activation fused ----------------
__device__ __forceinline__ float sigf(float x) { return 1.f / (1.f + expf(-x)); }

// F=64: one wave per node, 1 channel per lane
__global__ __launch_bounds__(256) void gather64_sig(const float* __restrict__ sup,
                                                    const int* __restrict__ row_ptr,
                                                    const int2* __restrict__ csr,
                                                    const float* __restrict__ b,
                                                    float* __restrict__ h) {
    int t = blockIdx.x * 256 + threadIdx.x;
    int node = t >> 6;
    int lane = t & 63;
    if (node >= N_NODES) return;
    int rs = row_ptr[node], re = row_ptr[node + 1];
    float acc = 0.f;
    for (int k = rs; k < re; k++) {
        int2 ewp = csr[k];
        float wt = __int_as_float(ewp.y);
        acc += sup[(long)ewp.x * 64 + lane] * wt;
    }
    h[(long)node * 64 + lane] = sigf(acc + b[lane]);
}

// F=128: one wave per node, float2 per lane
__global__ __launch_bounds__(256) void gather128_sig(const float* __restrict__ sup,
                                                     const int* __restrict__ row_ptr,
                                                     const int2* __restrict__ csr,
                                                     const float* __restrict__ b,
                                                     float* __restrict__ h) {
    int t = blockIdx.x * 256 + threadIdx.x;
    int node = t >> 6;
    int lane = t & 63;
    if (node >= N_NODES) return;
    int rs = row_ptr[node], re = row_ptr[node + 1];
    float acc0 = 0.f, acc1 = 0.f;
    for (int k = rs; k < re; k++) {
        int2 ewp = csr[k];
        float wt = __int_as_float(ewp.y);
        float2 v = ((const float2*)(sup + (long)ewp.x * 128))[lane];
        acc0 += v.x * wt;
        acc1 += v.y * wt;
    }
    float2 bv = ((const float2*)b)[lane];
    ((float2*)(h + (long)node * 128))[lane] = make_float2(sigf(acc0 + bv.x), sigf(acc1 + bv.y));
}

// F=32: two nodes per wave (sub-wave of 32), no activation (layer 3)
__global__ __launch_bounds__(256) void gather32(const float* __restrict__ sup,
                                                const int* __restrict__ row_ptr,
                                                const int2* __restrict__ csr,
                                                const float* __restrict__ b,
                                                float* __restrict__ out) {
    int t = blockIdx.x * 256 + threadIdx.x;
    int node = t >> 5;
    int lane = t & 31;
    if (node >= N_NODES) return;
    int rs = row_ptr[node], re = row_ptr[node + 1];
    float acc = 0.f;
    for (int k = rs; k < re; k++) {
        int2 ewp = csr[k];
        float wt = __int_as_float(ewp.y);
        acc += sup[(long)ewp.x * 32 + lane] * wt;
    }
    out[(long)node * 32 + lane] = acc + b[lane];
}

extern "C" void kernel_launch(void* const* d_in, const int* in_sizes, int n_in,
                              void* d_out, int out_size, void* d_ws, size_t ws_size,
                              hipStream_t stream) {
    const float* x  = (const float*)d_in[0];
    const int*   ei = (const int*)d_in[1];
    const float* ew = (const float*)d_in[2];
    const float* W1 = (const float*)d_in[3];
    const float* b1 = (const float*)d_in[4];
    const float* W2 = (const float*)d_in[5];
    const float* b2 = (const float*)d_in[6];
    const float* W3 = (const float*)d_in[7];
    const float* b3 = (const float*)d_in[8];

    const int* src = ei;            // edge_index[0]
    const int* dst = ei + N_EDGES;  // edge_index[1]

    float* out  = (float*)d_out;             // [N,32]
    float* feat = out + (long)N_NODES * 32;  // [N,128] = h2

    // workspace layout (all re-initialized every launch)
    float* ws0 = (float*)d_ws;                        // support, N*128 floats
    float* h1  = ws0 + (size_t)N_NODES * 128;         // N*64 floats
    int*   deg = (int*)(h1 + (size_t)N_NODES * 64);   // N ints
    int*   row_ptr = deg + N_NODES;                   // N+2 ints (padded even)
    int*   cursor  = row_ptr + N_NODES + 2;           // N ints
    int2*  csr     = (int2*)(cursor + N_NODES);       // E int2 (8B aligned: 150002 ints precede)

    const int B = 256;
    const int gN   = (N_NODES + B - 1) / B;           // 196
    const int gE   = (N_EDGES + B - 1) / B;           // 1954
    const int gW   = (N_NODES * 64 + B - 1) / B;      // one wave per node
    const int gHW  = (N_NODES * 32 + B - 1) / B;      // one half-wave per node

    // ---- CSR build (shared by all 3 layers) ----
    zero_deg<<<gN, B, 0, stream>>>(deg);
    hist_k<<<gE, B, 0, stream>>>(dst, deg);
    scan_k<<<1, 1024, 0, stream>>>(deg, row_ptr, cursor);
    reorder_k<<<gE, B, 0, stream>>>(src, dst, ew, cursor, csr);

    // ---- Layer 1: 128 -> 64, sigmoid ----
    gemm_128_64<<<gN, B, 0, stream>>>(x, W1, ws0, N_NODES);
    gather64_sig<<<gW, B, 0, stream>>>(ws0, row_ptr, csr, b1, h1);

    // ---- Layer 2: 64 -> 128, sigmoid -> feat ----
    gemm_64_128<<<(2 * N_NODES + B - 1) / B, B, 0, stream>>>(h1, W2, ws0, N_NODES);
    gather128_sig<<<gW, B, 0, stream>>>(ws0, row_ptr, csr, b2, feat);

    // ---- Layer 3: 128 -> 32, no activation -> out ----
    gemm_128_32<<<gN, B, 0, stream>>>(feat, W3, ws0, N_NODES);
    gather32<<<gHW, B, 0, stream>>>(ws0, row_ptr, csr, b3, out);
}

// Round 3
// 386.212 us; speedup vs baseline: 4.3815x; 1.3094x over previous
//
#include <hip/hip_runtime.h>
#include <math.h>

#define N_NODES 50000
#define N_EDGES 500000
#define NB_SCAN 196  // ceil(N_NODES/256)
// L1: support=x@W1 [N,64], agg, sigmoid
// L2: agg1=A@h1 [N,64], feat=sigmoid(agg1@W2+b2)  (re-associated)
// L3: support=feat@W3 [N,32], agg -> out

// ---------------- GEMM kernels ----------------
__global__ __launch_bounds__(256) void gemm_128_64(const float* __restrict__ X,
                                                   const float* __restrict__ W,
                                                   float* __restrict__ C, int n) {
    __shared__ float Wl[128 * 64];
    for (int i = threadIdx.x; i < 128 * 64; i += 256) Wl[i] = W[i];
    __syncthreads();
    int row = blockIdx.x * 256 + threadIdx.x;
    if (row >= n) return;
    const float4* xr = (const float4*)(X + (long)row * 128);
    float acc[64];
#pragma unroll
    for (int j = 0; j < 64; j++) acc[j] = 0.f;
    for (int k4 = 0; k4 < 32; k4++) {
        float4 xv = xr[k4];
        const float* w0 = &Wl[(k4 * 4 + 0) * 64];
        const float* w1 = &Wl[(k4 * 4 + 1) * 64];
        const float* w2 = &Wl[(k4 * 4 + 2) * 64];
        const float* w3 = &Wl[(k4 * 4 + 3) * 64];
#pragma unroll
        for (int j = 0; j < 64; j++)
            acc[j] += xv.x * w0[j] + xv.y * w1[j] + xv.z * w2[j] + xv.w * w3[j];
    }
    float* cr = C + (long)row * 64;
#pragma unroll
    for (int j = 0; j < 64; j++) cr[j] = acc[j];
}

__device__ __forceinline__ float sigf(float x) { return 1.f / (1.f + expf(-x)); }

// C = sigmoid(X@W + b), X:[n,64], W:[64,128]; thread = row-half
__global__ __launch_bounds__(256) void gemm_64_128_bs(const float* __restrict__ X,
                                                      const float* __restrict__ W,
                                                      const float* __restrict__ b,
                                                      float* __restrict__ C, int n) {
    __shared__ float Wl[64 * 128];
    for (int i = threadIdx.x; i < 64 * 128; i += 256) Wl[i] = W[i];
    __syncthreads();
    int t = blockIdx.x * 256 + threadIdx.x;
    int row = t >> 1;
    int half = (t & 1) * 64;
    if (row >= n) return;
    const float4* xr = (const float4*)(X + (long)row * 64);
    float acc[64];
#pragma unroll
    for (int j = 0; j < 64; j++) acc[j] = 0.f;
    for (int k4 = 0; k4 < 16; k4++) {
        float4 xv = xr[k4];
        const float* w0 = &Wl[(k4 * 4 + 0) * 128 + half];
        const float* w1 = &Wl[(k4 * 4 + 1) * 128 + half];
        const float* w2 = &Wl[(k4 * 4 + 2) * 128 + half];
        const float* w3 = &Wl[(k4 * 4 + 3) * 128 + half];
#pragma unroll
        for (int j = 0; j < 64; j++)
            acc[j] += xv.x * w0[j] + xv.y * w1[j] + xv.z * w2[j] + xv.w * w3[j];
    }
    float* cr = C + (long)row * 128 + half;
    const float* bp = b + half;
#pragma unroll
    for (int j = 0; j < 64; j++) cr[j] = sigf(acc[j] + bp[j]);
}

__global__ __launch_bounds__(256) void gemm_128_32(const float* __restrict__ X,
                                                   const float* __restrict__ W,
                                                   float* __restrict__ C, int n) {
    __shared__ float Wl[128 * 32];
    for (int i = threadIdx.x; i < 128 * 32; i += 256) Wl[i] = W[i];
    __syncthreads();
    int row = blockIdx.x * 256 + threadIdx.x;
    if (row >= n) return;
    const float4* xr = (const float4*)(X + (long)row * 128);
    float acc[32];
#pragma unroll
    for (int j = 0; j < 32; j++) acc[j] = 0.f;
    for (int k4 = 0; k4 < 32; k4++) {
        float4 xv = xr[k4];
        const float* w0 = &Wl[(k4 * 4 + 0) * 32];
        const float* w1 = &Wl[(k4 * 4 + 1) * 32];
        const float* w2 = &Wl[(k4 * 4 + 2) * 32];
        const float* w3 = &Wl[(k4 * 4 + 3) * 32];
#pragma unroll
        for (int j = 0; j < 32; j++)
            acc[j] += xv.x * w0[j] + xv.y * w1[j] + xv.z * w2[j] + xv.w * w3[j];
    }
    float* cr = C + (long)row * 32;
#pragma unroll
    for (int j = 0; j < 32; j++) cr[j] = acc[j];
}

// ---------------- CSR build (by dst), rebuilt every launch ----------------
__global__ __launch_bounds__(256) void zero_deg(int* __restrict__ deg) {
    int i = blockIdx.x * 256 + threadIdx.x;
    if (i < N_NODES) deg[i] = 0;
}

__global__ __launch_bounds__(256) void hist_k(const int* __restrict__ dst, int* __restrict__ deg) {
    int e = blockIdx.x * 256 + threadIdx.x;
    if (e < N_EDGES) atomicAdd(&deg[dst[e]], 1);
}

// parallel scan, stage 1: per-block sums (196 blocks x 256)
__global__ __launch_bounds__(256) void block_sum_k(const int* __restrict__ deg,
                                                   int* __restrict__ bsums) {
    __shared__ int red[256];
    int i = blockIdx.x * 256 + threadIdx.x;
    red[threadIdx.x] = (i < N_NODES) ? deg[i] : 0;
    __syncthreads();
    for (int s = 128; s > 0; s >>= 1) {
        if (threadIdx.x < s) red[threadIdx.x] += red[threadIdx.x + s];
        __syncthreads();
    }
    if (threadIdx.x == 0) bsums[blockIdx.x] = red[0];
}

// stage 2: exclusive scan of the 196 block sums (one block)
__global__ __launch_bounds__(256) void scan_bsums_k(int* __restrict__ bsums) {
    __shared__ int s[256];
    int t = threadIdx.x;
    s[t] = (t < NB_SCAN) ? bsums[t] : 0;
    __syncthreads();
    for (int off = 1; off < 256; off <<= 1) {
        int v = (t >= off) ? s[t - off] : 0;
        __syncthreads();
        s[t] += v;
        __syncthreads();
    }
    if (t < NB_SCAN) bsums[t] = (t == 0) ? 0 : s[t - 1];
}

// stage 3: per-block exclusive scan + block offset -> row_ptr, cursor
__global__ __launch_bounds__(256) void rowptr_k(const int* __restrict__ deg,
                                                const int* __restrict__ bsums,
                                                int* __restrict__ row_ptr,
                                                int* __restrict__ cursor) {
    __shared__ int s[256];
    int i = blockIdx.x * 256 + threadIdx.x;
    int t = threadIdx.x;
    int d = (i < N_NODES) ? deg[i] : 0;
    s[t] = d;
    __syncthreads();
    for (int off = 1; off < 256; off <<= 1) {
        int v = (t >= off) ? s[t - off] : 0;
        __syncthreads();
        s[t] += v;
        __syncthreads();
    }
    int excl = s[t] - d + bsums[blockIdx.x];
    if (i < N_NODES) {
        row_ptr[i] = excl;
        cursor[i] = excl;
        if (i == N_NODES - 1) row_ptr[N_NODES] = excl + d;
    }
}

// scatter edges into CSR slots: csr[pos] = (src, weight)
__global__ __launch_bounds__(256) void reorder_k(const int* __restrict__ src,
                                                 const int* __restrict__ dst,
                                                 const float* __restrict__ w,
                                                 int* __restrict__ cursor,
                                                 int2* __restrict__ csr) {
    int e = blockIdx.x * 256 + threadIdx.x;
    if (e >= N_EDGES) return;
    int pos = atomicAdd(&cursor[dst[e]], 1);
    csr[pos] = make_int2(src[e], __float_as_int(w[e]));
}

// ---------------- gather aggregation (no atomics) ----------------
// F=64 with fused bias+sigmoid (layer 1)
__global__ __launch_bounds__(256) void gather64_sig(const float* __restrict__ sup,
                                                    const int* __restrict__ row_ptr,
                                                    const int2* __restrict__ csr,
                                                    const float* __restrict__ b,
                                                    float* __restrict__ h) {
    int t = blockIdx.x * 256 + threadIdx.x;
    int node = t >> 6;
    int lane = t & 63;
    if (node >= N_NODES) return;
    int rs = row_ptr[node], re = row_ptr[node + 1];
    float acc = 0.f;
    for (int k = rs; k < re; k++) {
        int2 ewp = csr[k];
        float wt = __int_as_float(ewp.y);
        acc += sup[(long)ewp.x * 64 + lane] * wt;
    }
    h[(long)node * 64 + lane] = sigf(acc + b[lane]);
}

// F=64 plain (layer 2 pre-GEMM aggregation of h1)
__global__ __launch_bounds__(256) void gather64_plain(const float* __restrict__ sup,
                                                      const int* __restrict__ row_ptr,
                                                      const int2* __restrict__ csr,
                                                      float* __restrict__ aggout) {
    int t = blockIdx.x * 256 + threadIdx.x;
    int node = t >> 6;
    int lane = t & 63;
    if (node >= N_NODES) return;
    int rs = row_ptr[node], re = row_ptr[node + 1];
    float acc = 0.f;
    for (int k = rs; k < re; k++) {
        int2 ewp = csr[k];
        float wt = __int_as_float(ewp.y);
        acc += sup[(long)ewp.x * 64 + lane] * wt;
    }
    aggout[(long)node * 64 + lane] = acc;
}

// F=32, bias folded, no activation (layer 3)
__global__ __launch_bounds__(256) void gather32(const float* __restrict__ sup,
                                                const int* __restrict__ row_ptr,
                                                const int2* __restrict__ csr,
                                                const float* __restrict__ b,
                                                float* __restrict__ out) {
    int t = blockIdx.x * 256 + threadIdx.x;
    int node = t >> 5;
    int lane = t & 31;
    if (node >= N_NODES) return;
    int rs = row_ptr[node], re = row_ptr[node + 1];
    float acc = 0.f;
    for (int k = rs; k < re; k++) {
        int2 ewp = csr[k];
        float wt = __int_as_float(ewp.y);
        acc += sup[(long)ewp.x * 32 + lane] * wt;
    }
    out[(long)node * 32 + lane] = acc + b[lane];
}

extern "C" void kernel_launch(void* const* d_in, const int* in_sizes, int n_in,
                              void* d_out, int out_size, void* d_ws, size_t ws_size,
                              hipStream_t stream) {
    const float* x  = (const float*)d_in[0];
    const int*   ei = (const int*)d_in[1];
    const float* ew = (const float*)d_in[2];
    const float* W1 = (const float*)d_in[3];
    const float* b1 = (const float*)d_in[4];
    const float* W2 = (const float*)d_in[5];
    const float* b2 = (const float*)d_in[6];
    const float* W3 = (const float*)d_in[7];
    const float* b3 = (const float*)d_in[8];

    const int* src = ei;            // edge_index[0]
    const int* dst = ei + N_EDGES;  // edge_index[1]

    float* out  = (float*)d_out;             // [N,32]
    float* feat = out + (long)N_NODES * 32;  // [N,128] = h2

    // workspace layout
    float* ws0 = (float*)d_ws;                         // N*64 floats (support / agg1)
    float* h1  = ws0 + (size_t)N_NODES * 64;           // N*64 floats
    int*   deg = (int*)(h1 + (size_t)N_NODES * 64);    // N ints
    int*   row_ptr = deg + N_NODES;                    // N+2 ints (keep 8B parity)
    int*   cursor  = row_ptr + N_NODES + 2;            // N ints
    int*   bsums   = cursor + N_NODES;                 // NB_SCAN ints (pad to even)
    int2*  csr     = (int2*)(bsums + NB_SCAN + (NB_SCAN & 1));  // E int2, 8B aligned

    const int B = 256;
    const int gN  = (N_NODES + B - 1) / B;        // 196
    const int gE  = (N_EDGES + B - 1) / B;        // 1954
    const int gW  = (N_NODES * 64 + B - 1) / B;   // one wave per node
    const int gHW = (N_NODES * 32 + B - 1) / B;   // one half-wave per node

    // ---- CSR build (shared by all 3 layers) ----
    zero_deg<<<gN, B, 0, stream>>>(deg);
    hist_k<<<gE, B, 0, stream>>>(dst, deg);
    block_sum_k<<<NB_SCAN, B, 0, stream>>>(deg, bsums);
    scan_bsums_k<<<1, B, 0, stream>>>(bsums);
    rowptr_k<<<NB_SCAN, B, 0, stream>>>(deg, bsums, row_ptr, cursor);
    reorder_k<<<gE, B, 0, stream>>>(src, dst, ew, cursor, csr);

    // ---- Layer 1: support = x@W1 ; h1 = sigmoid(A@support + b1) ----
    gemm_128_64<<<gN, B, 0, stream>>>(x, W1, ws0, N_NODES);
    gather64_sig<<<gW, B, 0, stream>>>(ws0, row_ptr, csr, b1, h1);

    // ---- Layer 2 (re-associated): agg1 = A@h1 ; feat = sigmoid(agg1@W2 + b2) ----
    gather64_plain<<<gW, B, 0, stream>>>(h1, row_ptr, csr, ws0);
    gemm_64_128_bs<<<(2 * N_NODES + B - 1) / B, B, 0, stream>>>(ws0, W2, b2, feat, N_NODES);

    // ---- Layer 3: support = feat@W3 ; out = A@support + b3 ----
    gemm_128_32<<<gN, B, 0, stream>>>(feat, W3, ws0, N_NODES);
    gather32<<<gHW, B, 0, stream>>>(ws0, row_ptr, csr, b3, out);
}

// Round 4
// 352.290 us; speedup vs baseline: 4.8034x; 1.0963x over previous
//
#include <hip/hip_runtime.h>
#include <math.h>

#define N_NODES 50000
#define N_EDGES 500000
#define NB_SCAN 196  // ceil(N_NODES/256)
// L1: sup1=x@W1 [N,64] (bf16), h1=sigmoid(A@sup1+b1) (bf16)
// L2: agg1=A@h1 [N,64] (f32), feat=sigmoid(agg1@W2+b2) (f32, output)
// L3: sup3=feat@W3 [N,32] (bf16), out=A@sup3+b3 (f32, output)

// ---- bf16 helpers (RNE) ----
__device__ __forceinline__ unsigned short f2bf(float f) {
    unsigned u = __float_as_uint(f);
    return (unsigned short)((u + 0x7fffu + ((u >> 16) & 1u)) >> 16);
}
__device__ __forceinline__ float bf2f(unsigned short s) {
    return __uint_as_float((unsigned)s << 16);
}
__device__ __forceinline__ float sigf(float x) { return 1.f / (1.f + expf(-x)); }

// ---------------- GEMM kernels ----------------
// C_bf16[n,64] = X[n,128] @ W[128,64]
__global__ __launch_bounds__(256) void gemm_128_64_bf(const float* __restrict__ X,
                                                      const float* __restrict__ W,
                                                      unsigned short* __restrict__ C, int n) {
    __shared__ float Wl[128 * 64];
    for (int i = threadIdx.x; i < 128 * 64; i += 256) Wl[i] = W[i];
    __syncthreads();
    int row = blockIdx.x * 256 + threadIdx.x;
    if (row >= n) return;
    const float4* xr = (const float4*)(X + (long)row * 128);
    float acc[64];
#pragma unroll
    for (int j = 0; j < 64; j++) acc[j] = 0.f;
    for (int k4 = 0; k4 < 32; k4++) {
        float4 xv = xr[k4];
        const float* w0 = &Wl[(k4 * 4 + 0) * 64];
        const float* w1 = &Wl[(k4 * 4 + 1) * 64];
        const float* w2 = &Wl[(k4 * 4 + 2) * 64];
        const float* w3 = &Wl[(k4 * 4 + 3) * 64];
#pragma unroll
        for (int j = 0; j < 64; j++)
            acc[j] += xv.x * w0[j] + xv.y * w1[j] + xv.z * w2[j] + xv.w * w3[j];
    }
    ushort2* cr = (ushort2*)(C + (long)row * 64);
#pragma unroll
    for (int j = 0; j < 32; j++) cr[j] = make_ushort2(f2bf(acc[2 * j]), f2bf(acc[2 * j + 1]));
}

// C[n,128] = sigmoid(X[n,64] @ W[64,128] + b) (fp32 out: this IS `feat`)
__global__ __launch_bounds__(256) void gemm_64_128_bs(const float* __restrict__ X,
                                                      const float* __restrict__ W,
                                                      const float* __restrict__ b,
                                                      float* __restrict__ C, int n) {
    __shared__ float Wl[64 * 128];
    for (int i = threadIdx.x; i < 64 * 128; i += 256) Wl[i] = W[i];
    __syncthreads();
    int t = blockIdx.x * 256 + threadIdx.x;
    int row = t >> 1;
    int half = (t & 1) * 64;
    if (row >= n) return;
    const float4* xr = (const float4*)(X + (long)row * 64);
    float acc[64];
#pragma unroll
    for (int j = 0; j < 64; j++) acc[j] = 0.f;
    for (int k4 = 0; k4 < 16; k4++) {
        float4 xv = xr[k4];
        const float* w0 = &Wl[(k4 * 4 + 0) * 128 + half];
        const float* w1 = &Wl[(k4 * 4 + 1) * 128 + half];
        const float* w2 = &Wl[(k4 * 4 + 2) * 128 + half];
        const float* w3 = &Wl[(k4 * 4 + 3) * 128 + half];
#pragma unroll
        for (int j = 0; j < 64; j++)
            acc[j] += xv.x * w0[j] + xv.y * w1[j] + xv.z * w2[j] + xv.w * w3[j];
    }
    float* cr = C + (long)row * 128 + half;
    const float* bp = b + half;
#pragma unroll
    for (int j = 0; j < 64; j++) cr[j] = sigf(acc[j] + bp[j]);
}

// C_bf16[n,32] = X[n,128] @ W[128,32]
__global__ __launch_bounds__(256) void gemm_128_32_bf(const float* __restrict__ X,
                                                      const float* __restrict__ W,
                                                      unsigned short* __restrict__ C, int n) {
    __shared__ float Wl[128 * 32];
    for (int i = threadIdx.x; i < 128 * 32; i += 256) Wl[i] = W[i];
    __syncthreads();
    int row = blockIdx.x * 256 + threadIdx.x;
    if (row >= n) return;
    const float4* xr = (const float4*)(X + (long)row * 128);
    float acc[32];
#pragma unroll
    for (int j = 0; j < 32; j++) acc[j] = 0.f;
    for (int k4 = 0; k4 < 32; k4++) {
        float4 xv = xr[k4];
        const float* w0 = &Wl[(k4 * 4 + 0) * 32];
        const float* w1 = &Wl[(k4 * 4 + 1) * 32];
        const float* w2 = &Wl[(k4 * 4 + 2) * 32];
        const float* w3 = &Wl[(k4 * 4 + 3) * 32];
#pragma unroll
        for (int j = 0; j < 32; j++)
            acc[j] += xv.x * w0[j] + xv.y * w1[j] + xv.z * w2[j] + xv.w * w3[j];
    }
    ushort2* cr = (ushort2*)(C + (long)row * 32);
#pragma unroll
    for (int j = 0; j < 16; j++) cr[j] = make_ushort2(f2bf(acc[2 * j]), f2bf(acc[2 * j + 1]));
}

// ---------------- CSR build (by dst), rebuilt every launch ----------------
__global__ __launch_bounds__(256) void zero_deg(int* __restrict__ deg) {
    int i = blockIdx.x * 256 + threadIdx.x;
    if (i < N_NODES) deg[i] = 0;
}

__global__ __launch_bounds__(256) void hist_k(const int* __restrict__ dst, int* __restrict__ deg) {
    int e = blockIdx.x * 256 + threadIdx.x;
    if (e < N_EDGES) atomicAdd(&deg[dst[e]], 1);
}

__global__ __launch_bounds__(256) void block_sum_k(const int* __restrict__ deg,
                                                   int* __restrict__ bsums) {
    __shared__ int red[256];
    int i = blockIdx.x * 256 + threadIdx.x;
    red[threadIdx.x] = (i < N_NODES) ? deg[i] : 0;
    __syncthreads();
    for (int s = 128; s > 0; s >>= 1) {
        if (threadIdx.x < s) red[threadIdx.x] += red[threadIdx.x + s];
        __syncthreads();
    }
    if (threadIdx.x == 0) bsums[blockIdx.x] = red[0];
}

__global__ __launch_bounds__(256) void scan_bsums_k(int* __restrict__ bsums) {
    __shared__ int s[256];
    int t = threadIdx.x;
    s[t] = (t < NB_SCAN) ? bsums[t] : 0;
    __syncthreads();
    for (int off = 1; off < 256; off <<= 1) {
        int v = (t >= off) ? s[t - off] : 0;
        __syncthreads();
        s[t] += v;
        __syncthreads();
    }
    if (t < NB_SCAN) bsums[t] = (t == 0) ? 0 : s[t - 1];
}

__global__ __launch_bounds__(256) void rowptr_k(const int* __restrict__ deg,
                                                const int* __restrict__ bsums,
                                                int* __restrict__ row_ptr,
                                                int* __restrict__ cursor) {
    __shared__ int s[256];
    int i = blockIdx.x * 256 + threadIdx.x;
    int t = threadIdx.x;
    int d = (i < N_NODES) ? deg[i] : 0;
    s[t] = d;
    __syncthreads();
    for (int off = 1; off < 256; off <<= 1) {
        int v = (t >= off) ? s[t - off] : 0;
        __syncthreads();
        s[t] += v;
        __syncthreads();
    }
    int excl = s[t] - d + bsums[blockIdx.x];
    if (i < N_NODES) {
        row_ptr[i] = excl;
        cursor[i] = excl;
        if (i == N_NODES - 1) row_ptr[N_NODES] = excl + d;
    }
}

__global__ __launch_bounds__(256) void reorder_k(const int* __restrict__ src,
                                                 const int* __restrict__ dst,
                                                 const float* __restrict__ w,
                                                 int* __restrict__ cursor,
                                                 int2* __restrict__ csr) {
    int e = blockIdx.x * 256 + threadIdx.x;
    if (e >= N_EDGES) return;
    int pos = atomicAdd(&cursor[dst[e]], 1);
    csr[pos] = make_int2(src[e], __float_as_int(w[e]));
}

// ---------------- gather aggregation (bf16 payload, unroll-4, no atomics) ----------------
// Layer 1: h1_bf16 = sigmoid(A @ sup_bf16 + b1); one wave per node, lane = feature
__global__ __launch_bounds__(256) void gather64_sig_bf(const unsigned short* __restrict__ sup,
                                                       const int* __restrict__ row_ptr,
                                                       const int2* __restrict__ csr,
                                                       const float* __restrict__ b,
                                                       unsigned short* __restrict__ h) {
    int t = blockIdx.x * 256 + threadIdx.x;
    int node = t >> 6;
    int lane = t & 63;
    if (node >= N_NODES) return;
    int rs = row_ptr[node], re = row_ptr[node + 1];
    float acc = 0.f;
    int k = rs;
    for (; k + 4 <= re; k += 4) {
        int2 e0 = csr[k], e1 = csr[k + 1], e2 = csr[k + 2], e3 = csr[k + 3];
        float v0 = bf2f(sup[(long)e0.x * 64 + lane]);
        float v1 = bf2f(sup[(long)e1.x * 64 + lane]);
        float v2 = bf2f(sup[(long)e2.x * 64 + lane]);
        float v3 = bf2f(sup[(long)e3.x * 64 + lane]);
        acc += v0 * __int_as_float(e0.y) + v1 * __int_as_float(e1.y) +
               v2 * __int_as_float(e2.y) + v3 * __int_as_float(e3.y);
    }
    for (; k < re; k++) {
        int2 e0 = csr[k];
        acc += bf2f(sup[(long)e0.x * 64 + lane]) * __int_as_float(e0.y);
    }
    h[(long)node * 64 + lane] = f2bf(sigf(acc + b[lane]));
}

// Layer 2 pre-GEMM: agg1_f32 = A @ h1_bf16
__global__ __launch_bounds__(256) void gather64_plain_bf(const unsigned short* __restrict__ sup,
                                                         const int* __restrict__ row_ptr,
                                                         const int2* __restrict__ csr,
                                                         float* __restrict__ aggout) {
    int t = blockIdx.x * 256 + threadIdx.x;
    int node = t >> 6;
    int lane = t & 63;
    if (node >= N_NODES) return;
    int rs = row_ptr[node], re = row_ptr[node + 1];
    float acc = 0.f;
    int k = rs;
    for (; k + 4 <= re; k += 4) {
        int2 e0 = csr[k], e1 = csr[k + 1], e2 = csr[k + 2], e3 = csr[k + 3];
        float v0 = bf2f(sup[(long)e0.x * 64 + lane]);
        float v1 = bf2f(sup[(long)e1.x * 64 + lane]);
        float v2 = bf2f(sup[(long)e2.x * 64 + lane]);
        float v3 = bf2f(sup[(long)e3.x * 64 + lane]);
        acc += v0 * __int_as_float(e0.y) + v1 * __int_as_float(e1.y) +
               v2 * __int_as_float(e2.y) + v3 * __int_as_float(e3.y);
    }
    for (; k < re; k++) {
        int2 e0 = csr[k];
        acc += bf2f(sup[(long)e0.x * 64 + lane]) * __int_as_float(e0.y);
    }
    aggout[(long)node * 64 + lane] = acc;
}

// Layer 3: out_f32 = A @ sup3_bf16 + b3; half-wave (32 lanes) per node
__global__ __launch_bounds__(256) void gather32_bf(const unsigned short* __restrict__ sup,
                                                   const int* __restrict__ row_ptr,
                                                   const int2* __restrict__ csr,
                                                   const float* __restrict__ b,
                                                   float* __restrict__ out) {
    int t = blockIdx.x * 256 + threadIdx.x;
    int node = t >> 5;
    int lane = t & 31;
    if (node >= N_NODES) return;
    int rs = row_ptr[node], re = row_ptr[node + 1];
    float acc = 0.f;
    int k = rs;
    for (; k + 4 <= re; k += 4) {
        int2 e0 = csr[k], e1 = csr[k + 1], e2 = csr[k + 2], e3 = csr[k + 3];
        float v0 = bf2f(sup[(long)e0.x * 32 + lane]);
        float v1 = bf2f(sup[(long)e1.x * 32 + lane]);
        float v2 = bf2f(sup[(long)e2.x * 32 + lane]);
        float v3 = bf2f(sup[(long)e3.x * 32 + lane]);
        acc += v0 * __int_as_float(e0.y) + v1 * __int_as_float(e1.y) +
               v2 * __int_as_float(e2.y) + v3 * __int_as_float(e3.y);
    }
    for (; k < re; k++) {
        int2 e0 = csr[k];
        acc += bf2f(sup[(long)e0.x * 32 + lane]) * __int_as_float(e0.y);
    }
    out[(long)node * 32 + lane] = acc + b[lane];
}

extern "C" void kernel_launch(void* const* d_in, const int* in_sizes, int n_in,
                              void* d_out, int out_size, void* d_ws, size_t ws_size,
                              hipStream_t stream) {
    const float* x  = (const float*)d_in[0];
    const int*   ei = (const int*)d_in[1];
    const float* ew = (const float*)d_in[2];
    const float* W1 = (const float*)d_in[3];
    const float* b1 = (const float*)d_in[4];
    const float* W2 = (const float*)d_in[5];
    const float* b2 = (const float*)d_in[6];
    const float* W3 = (const float*)d_in[7];
    const float* b3 = (const float*)d_in[8];

    const int* src = ei;            // edge_index[0]
    const int* dst = ei + N_EDGES;  // edge_index[1]

    float* out  = (float*)d_out;             // [N,32]
    float* feat = out + (long)N_NODES * 32;  // [N,128] = h2 (fp32, output)

    // workspace layout (8B-alignment audited)
    float*          agg1    = (float*)d_ws;                              // N*64 f32
    unsigned short* sup1    = (unsigned short*)(agg1 + (size_t)N_NODES * 64);  // N*64 bf16
    unsigned short* h1      = sup1 + (size_t)N_NODES * 64;               // N*64 bf16
    unsigned short* sup3    = h1 + (size_t)N_NODES * 64;                 // N*32 bf16
    int*            deg     = (int*)(sup3 + (size_t)N_NODES * 32);       // N ints
    int*            row_ptr = deg + N_NODES;                             // N+2 ints
    int*            cursor  = row_ptr + N_NODES + 2;                     // N ints
    int*            bsums   = cursor + N_NODES;                          // 196 ints (even)
    int2*           csr     = (int2*)(bsums + NB_SCAN);                  // E int2 (8B aligned)

    const int B = 256;
    const int gN  = (N_NODES + B - 1) / B;        // 196
    const int gE  = (N_EDGES + B - 1) / B;        // 1954
    const int gW  = (N_NODES * 64 + B - 1) / B;   // one wave per node
    const int gHW = (N_NODES * 32 + B - 1) / B;   // one half-wave per node

    // ---- CSR build (shared by all 3 layers) ----
    zero_deg<<<gN, B, 0, stream>>>(deg);
    hist_k<<<gE, B, 0, stream>>>(dst, deg);
    block_sum_k<<<NB_SCAN, B, 0, stream>>>(deg, bsums);
    scan_bsums_k<<<1, B, 0, stream>>>(bsums);
    rowptr_k<<<NB_SCAN, B, 0, stream>>>(deg, bsums, row_ptr, cursor);
    reorder_k<<<gE, B, 0, stream>>>(src, dst, ew, cursor, csr);

    // ---- Layer 1: sup1 = bf16(x@W1) ; h1 = bf16(sigmoid(A@sup1 + b1)) ----
    gemm_128_64_bf<<<gN, B, 0, stream>>>(x, W1, sup1, N_NODES);
    gather64_sig_bf<<<gW, B, 0, stream>>>(sup1, row_ptr, csr, b1, h1);

    // ---- Layer 2 (re-associated): agg1 = A@h1 ; feat = sigmoid(agg1@W2 + b2) ----
    gather64_plain_bf<<<gW, B, 0, stream>>>(h1, row_ptr, csr, agg1);
    gemm_64_128_bs<<<(2 * N_NODES + B - 1) / B, B, 0, stream>>>(agg1, W2, b2, feat, N_NODES);

    // ---- Layer 3: sup3 = bf16(feat@W3) ; out = A@sup3 + b3 ----
    gemm_128_32_bf<<<gN, B, 0, stream>>>(feat, W3, sup3, N_NODES);
    gather32_bf<<<gHW, B, 0, stream>>>(sup3, row_ptr, csr, b3, out);
}

// Round 5
// 295.625 us; speedup vs baseline: 5.7241x; 1.1917x over previous
//
#include <hip/hip_runtime.h>
#include <math.h>

#define N_NODES 50000
#define N_EDGES 500000
#define NB_SCAN 196  // ceil(N_NODES/256)
// L1: sup1=x@W1 [N,64] (bf16), h1=sigmoid(A@sup1+b1) (bf16)
// L2: agg1=A@h1 [N,64] (f32), feat=sigmoid(agg1@W2+b2) (f32, output)
// L3: sup3=feat@W3 [N,32] (bf16), out=A@sup3+b3 (f32, output)

// ---- bf16 helpers (RNE) ----
__device__ __forceinline__ unsigned f2bf(float f) {
    unsigned u = __float_as_uint(f);
    return (u + 0x7fffu + ((u >> 16) & 1u)) >> 16;
}
__device__ __forceinline__ float bf2f(unsigned short s) {
    return __uint_as_float((unsigned)s << 16);
}
__device__ __forceinline__ float sigf(float x) { return 1.f / (1.f + expf(-x)); }

// ---------------- GEMM kernels: 16 output cols per thread ----------------
// C_bf16[n,64] = X[n,128] @ W[128,64]; 4 chunks/row, 64 rows/block
__global__ __launch_bounds__(256) void gemm_128_64_bf(const float* __restrict__ X,
                                                      const float* __restrict__ W,
                                                      unsigned short* __restrict__ C, int n) {
    __shared__ float Wl[128 * 64];
    for (int i = threadIdx.x; i < 128 * 64; i += 256) Wl[i] = W[i];
    __syncthreads();
    int t = blockIdx.x * 256 + threadIdx.x;
    int row = t >> 2;
    int c0 = (t & 3) * 16;
    if (row >= n) return;
    const float4* xr = (const float4*)(X + (long)row * 128);
    float acc[16];
#pragma unroll
    for (int j = 0; j < 16; j++) acc[j] = 0.f;
    for (int k4 = 0; k4 < 32; k4++) {
        float4 xv = xr[k4];
        const float* w0 = &Wl[(k4 * 4 + 0) * 64 + c0];
        const float* w1 = &Wl[(k4 * 4 + 1) * 64 + c0];
        const float* w2 = &Wl[(k4 * 4 + 2) * 64 + c0];
        const float* w3 = &Wl[(k4 * 4 + 3) * 64 + c0];
#pragma unroll
        for (int j = 0; j < 16; j++)
            acc[j] += xv.x * w0[j] + xv.y * w1[j] + xv.z * w2[j] + xv.w * w3[j];
    }
    unsigned u[8];
#pragma unroll
    for (int j = 0; j < 8; j++) u[j] = f2bf(acc[2 * j]) | (f2bf(acc[2 * j + 1]) << 16);
    uint4* cr = (uint4*)(C + (long)row * 64 + c0);
    cr[0] = make_uint4(u[0], u[1], u[2], u[3]);
    cr[1] = make_uint4(u[4], u[5], u[6], u[7]);
}

// feat[n,128] = sigmoid(X[n,64] @ W[64,128] + b); 8 chunks/row, 32 rows/block
__global__ __launch_bounds__(256) void gemm_64_128_bs(const float* __restrict__ X,
                                                      const float* __restrict__ W,
                                                      const float* __restrict__ b,
                                                      float* __restrict__ C, int n) {
    __shared__ float Wl[64 * 128];
    for (int i = threadIdx.x; i < 64 * 128; i += 256) Wl[i] = W[i];
    __syncthreads();
    int t = blockIdx.x * 256 + threadIdx.x;
    int row = t >> 3;
    int c0 = (t & 7) * 16;
    if (row >= n) return;
    const float4* xr = (const float4*)(X + (long)row * 64);
    float acc[16];
#pragma unroll
    for (int j = 0; j < 16; j++) acc[j] = 0.f;
    for (int k4 = 0; k4 < 16; k4++) {
        float4 xv = xr[k4];
        const float* w0 = &Wl[(k4 * 4 + 0) * 128 + c0];
        const float* w1 = &Wl[(k4 * 4 + 1) * 128 + c0];
        const float* w2 = &Wl[(k4 * 4 + 2) * 128 + c0];
        const float* w3 = &Wl[(k4 * 4 + 3) * 128 + c0];
#pragma unroll
        for (int j = 0; j < 16; j++)
            acc[j] += xv.x * w0[j] + xv.y * w1[j] + xv.z * w2[j] + xv.w * w3[j];
    }
    float* cr = C + (long)row * 128 + c0;
    const float* bp = b + c0;
#pragma unroll
    for (int j = 0; j < 16; j++) acc[j] = sigf(acc[j] + bp[j]);
    float4* cv = (float4*)cr;
#pragma unroll
    for (int j = 0; j < 4; j++)
        cv[j] = make_float4(acc[4 * j], acc[4 * j + 1], acc[4 * j + 2], acc[4 * j + 3]);
}

// C_bf16[n,32] = X[n,128] @ W[128,32]; 2 chunks/row, 128 rows/block
__global__ __launch_bounds__(256) void gemm_128_32_bf(const float* __restrict__ X,
                                                      const float* __restrict__ W,
                                                      unsigned short* __restrict__ C, int n) {
    __shared__ float Wl[128 * 32];
    for (int i = threadIdx.x; i < 128 * 32; i += 256) Wl[i] = W[i];
    __syncthreads();
    int t = blockIdx.x * 256 + threadIdx.x;
    int row = t >> 1;
    int c0 = (t & 1) * 16;
    if (row >= n) return;
    const float4* xr = (const float4*)(X + (long)row * 128);
    float acc[16];
#pragma unroll
    for (int j = 0; j < 16; j++) acc[j] = 0.f;
    for (int k4 = 0; k4 < 32; k4++) {
        float4 xv = xr[k4];
        const float* w0 = &Wl[(k4 * 4 + 0) * 32 + c0];
        const float* w1 = &Wl[(k4 * 4 + 1) * 32 + c0];
        const float* w2 = &Wl[(k4 * 4 + 2) * 32 + c0];
        const float* w3 = &Wl[(k4 * 4 + 3) * 32 + c0];
#pragma unroll
        for (int j = 0; j < 16; j++)
            acc[j] += xv.x * w0[j] + xv.y * w1[j] + xv.z * w2[j] + xv.w * w3[j];
    }
    unsigned u[8];
#pragma unroll
    for (int j = 0; j < 8; j++) u[j] = f2bf(acc[2 * j]) | (f2bf(acc[2 * j + 1]) << 16);
    uint4* cr = (uint4*)(C + (long)row * 32 + c0);
    cr[0] = make_uint4(u[0], u[1], u[2], u[3]);
    cr[1] = make_uint4(u[4], u[5], u[6], u[7]);
}

// ---------------- CSR build (by dst), rebuilt every launch ----------------
__global__ __launch_bounds__(256) void zero_deg(int* __restrict__ deg) {
    int i = blockIdx.x * 256 + threadIdx.x;
    if (i < N_NODES) deg[i] = 0;
}

__global__ __launch_bounds__(256) void hist_k(const int* __restrict__ dst, int* __restrict__ deg) {
    int e = blockIdx.x * 256 + threadIdx.x;
    if (e < N_EDGES) atomicAdd(&deg[dst[e]], 1);
}

__global__ __launch_bounds__(256) void block_sum_k(const int* __restrict__ deg,
                                                   int* __restrict__ bsums) {
    __shared__ int red[256];
    int i = blockIdx.x * 256 + threadIdx.x;
    red[threadIdx.x] = (i < N_NODES) ? deg[i] : 0;
    __syncthreads();
    for (int s = 128; s > 0; s >>= 1) {
        if (threadIdx.x < s) red[threadIdx.x] += red[threadIdx.x + s];
        __syncthreads();
    }
    if (threadIdx.x == 0) bsums[blockIdx.x] = red[0];
}

__global__ __launch_bounds__(256) void scan_bsums_k(int* __restrict__ bsums) {
    __shared__ int s[256];
    int t = threadIdx.x;
    s[t] = (t < NB_SCAN) ? bsums[t] : 0;
    __syncthreads();
    for (int off = 1; off < 256; off <<= 1) {
        int v = (t >= off) ? s[t - off] : 0;
        __syncthreads();
        s[t] += v;
        __syncthreads();
    }
    if (t < NB_SCAN) bsums[t] = (t == 0) ? 0 : s[t - 1];
}

__global__ __launch_bounds__(256) void rowptr_k(const int* __restrict__ deg,
                                                const int* __restrict__ bsums,
                                                int* __restrict__ row_ptr,
                                                int* __restrict__ cursor) {
    __shared__ int s[256];
    int i = blockIdx.x * 256 + threadIdx.x;
    int t = threadIdx.x;
    int d = (i < N_NODES) ? deg[i] : 0;
    s[t] = d;
    __syncthreads();
    for (int off = 1; off < 256; off <<= 1) {
        int v = (t >= off) ? s[t - off] : 0;
        __syncthreads();
        s[t] += v;
        __syncthreads();
    }
    int excl = s[t] - d + bsums[blockIdx.x];
    if (i < N_NODES) {
        row_ptr[i] = excl;
        cursor[i] = excl;
        if (i == N_NODES - 1) row_ptr[N_NODES] = excl + d;
    }
}

__global__ __launch_bounds__(256) void reorder_k(const int* __restrict__ src,
                                                 const int* __restrict__ dst,
                                                 const float* __restrict__ w,
                                                 int* __restrict__ cursor,
                                                 int2* __restrict__ csr) {
    int e = blockIdx.x * 256 + threadIdx.x;
    if (e >= N_EDGES) return;
    int pos = atomicAdd(&cursor[dst[e]], 1);
    csr[pos] = make_int2(src[e], __float_as_int(w[e]));
}

// ---------------- gather aggregation (bf16 payload, unroll-4, no atomics) ----------------
__global__ __launch_bounds__(256) void gather64_sig_bf(const unsigned short* __restrict__ sup,
                                                       const int* __restrict__ row_ptr,
                                                       const int2* __restrict__ csr,
                                                       const float* __restrict__ b,
                                                       unsigned short* __restrict__ h) {
    int t = blockIdx.x * 256 + threadIdx.x;
    int node = t >> 6;
    int lane = t & 63;
    if (node >= N_NODES) return;
    int rs = row_ptr[node], re = row_ptr[node + 1];
    float acc = 0.f;
    int k = rs;
    for (; k + 4 <= re; k += 4) {
        int2 e0 = csr[k], e1 = csr[k + 1], e2 = csr[k + 2], e3 = csr[k + 3];
        float v0 = bf2f(sup[(long)e0.x * 64 + lane]);
        float v1 = bf2f(sup[(long)e1.x * 64 + lane]);
        float v2 = bf2f(sup[(long)e2.x * 64 + lane]);
        float v3 = bf2f(sup[(long)e3.x * 64 + lane]);
        acc += v0 * __int_as_float(e0.y) + v1 * __int_as_float(e1.y) +
               v2 * __int_as_float(e2.y) + v3 * __int_as_float(e3.y);
    }
    for (; k < re; k++) {
        int2 e0 = csr[k];
        acc += bf2f(sup[(long)e0.x * 64 + lane]) * __int_as_float(e0.y);
    }
    h[(long)node * 64 + lane] = (unsigned short)f2bf(sigf(acc + b[lane]));
}

__global__ __launch_bounds__(256) void gather64_plain_bf(const unsigned short* __restrict__ sup,
                                                         const int* __restrict__ row_ptr,
                                                         const int2* __restrict__ csr,
                                                         float* __restrict__ aggout) {
    int t = blockIdx.x * 256 + threadIdx.x;
    int node = t >> 6;
    int lane = t & 63;
    if (node >= N_NODES) return;
    int rs = row_ptr[node], re = row_ptr[node + 1];
    float acc = 0.f;
    int k = rs;
    for (; k + 4 <= re; k += 4) {
        int2 e0 = csr[k], e1 = csr[k + 1], e2 = csr[k + 2], e3 = csr[k + 3];
        float v0 = bf2f(sup[(long)e0.x * 64 + lane]);
        float v1 = bf2f(sup[(long)e1.x * 64 + lane]);
        float v2 = bf2f(sup[(long)e2.x * 64 + lane]);
        float v3 = bf2f(sup[(long)e3.x * 64 + lane]);
        acc += v0 * __int_as_float(e0.y) + v1 * __int_as_float(e1.y) +
               v2 * __int_as_float(e2.y) + v3 * __int_as_float(e3.y);
    }
    for (; k < re; k++) {
        int2 e0 = csr[k];
        acc += bf2f(sup[(long)e0.x * 64 + lane]) * __int_as_float(e0.y);
    }
    aggout[(long)node * 64 + lane] = acc;
}

__global__ __launch_bounds__(256) void gather32_bf(const unsigned short* __restrict__ sup,
                                                   const int* __restrict__ row_ptr,
                                                   const int2* __restrict__ csr,
                                                   const float* __restrict__ b,
                                                   float* __restrict__ out) {
    int t = blockIdx.x * 256 + threadIdx.x;
    int node = t >> 5;
    int lane = t & 31;
    if (node >= N_NODES) return;
    int rs = row_ptr[node], re = row_ptr[node + 1];
    float acc = 0.f;
    int k = rs;
    for (; k + 4 <= re; k += 4) {
        int2 e0 = csr[k], e1 = csr[k + 1], e2 = csr[k + 2], e3 = csr[k + 3];
        float v0 = bf2f(sup[(long)e0.x * 32 + lane]);
        float v1 = bf2f(sup[(long)e1.x * 32 + lane]);
        float v2 = bf2f(sup[(long)e2.x * 32 + lane]);
        float v3 = bf2f(sup[(long)e3.x * 32 + lane]);
        acc += v0 * __int_as_float(e0.y) + v1 * __int_as_float(e1.y) +
               v2 * __int_as_float(e2.y) + v3 * __int_as_float(e3.y);
    }
    for (; k < re; k++) {
        int2 e0 = csr[k];
        acc += bf2f(sup[(long)e0.x * 32 + lane]) * __int_as_float(e0.y);
    }
    out[(long)node * 32 + lane] = acc + b[lane];
}

extern "C" void kernel_launch(void* const* d_in, const int* in_sizes, int n_in,
                              void* d_out, int out_size, void* d_ws, size_t ws_size,
                              hipStream_t stream) {
    const float* x  = (const float*)d_in[0];
    const int*   ei = (const int*)d_in[1];
    const float* ew = (const float*)d_in[2];
    const float* W1 = (const float*)d_in[3];
    const float* b1 = (const float*)d_in[4];
    const float* W2 = (const float*)d_in[5];
    const float* b2 = (const float*)d_in[6];
    const float* W3 = (const float*)d_in[7];
    const float* b3 = (const float*)d_in[8];

    const int* src = ei;            // edge_index[0]
    const int* dst = ei + N_EDGES;  // edge_index[1]

    float* out  = (float*)d_out;             // [N,32]
    float* feat = out + (long)N_NODES * 32;  // [N,128] = h2 (fp32, output)

    // workspace layout
    float*          agg1    = (float*)d_ws;                              // N*64 f32
    unsigned short* sup1    = (unsigned short*)(agg1 + (size_t)N_NODES * 64);  // N*64 bf16
    unsigned short* h1      = sup1 + (size_t)N_NODES * 64;               // N*64 bf16
    unsigned short* sup3    = h1 + (size_t)N_NODES * 64;                 // N*32 bf16
    int*            deg     = (int*)(sup3 + (size_t)N_NODES * 32);       // N ints
    int*            row_ptr = deg + N_NODES;                             // N+2 ints
    int*            cursor  = row_ptr + N_NODES + 2;                     // N ints
    int*            bsums   = cursor + N_NODES;                          // 196 ints (even)
    int2*           csr     = (int2*)(bsums + NB_SCAN);                  // E int2 (8B aligned)

    const int B = 256;
    const int gN  = (N_NODES + B - 1) / B;        // 196
    const int gE  = (N_EDGES + B - 1) / B;        // 1954
    const int gW  = (N_NODES * 64 + B - 1) / B;   // one wave per node
    const int gHW = (N_NODES * 32 + B - 1) / B;   // one half-wave per node
    const int g1  = (N_NODES * 4 + B - 1) / B;    // 782  (4 chunks/row)
    const int g2  = (N_NODES * 8 + B - 1) / B;    // 1563 (8 chunks/row)
    const int g3  = (N_NODES * 2 + B - 1) / B;    // 391  (2 chunks/row)

    // ---- CSR build (shared by all 3 layers) ----
    zero_deg<<<gN, B, 0, stream>>>(deg);
    hist_k<<<gE, B, 0, stream>>>(dst, deg);
    block_sum_k<<<NB_SCAN, B, 0, stream>>>(deg, bsums);
    scan_bsums_k<<<1, B, 0, stream>>>(bsums);
    rowptr_k<<<NB_SCAN, B, 0, stream>>>(deg, bsums, row_ptr, cursor);
    reorder_k<<<gE, B, 0, stream>>>(src, dst, ew, cursor, csr);

    // ---- Layer 1: sup1 = bf16(x@W1) ; h1 = bf16(sigmoid(A@sup1 + b1)) ----
    gemm_128_64_bf<<<g1, B, 0, stream>>>(x, W1, sup1, N_NODES);
    gather64_sig_bf<<<gW, B, 0, stream>>>(sup1, row_ptr, csr, b1, h1);

    // ---- Layer 2 (re-associated): agg1 = A@h1 ; feat = sigmoid(agg1@W2 + b2) ----
    gather64_plain_bf<<<gW, B, 0, stream>>>(h1, row_ptr, csr, agg1);
    gemm_64_128_bs<<<g2, B, 0, stream>>>(agg1, W2, b2, feat, N_NODES);

    // ---- Layer 3: sup3 = bf16(feat@W3) ; out = A@sup3 + b3 ----
    gemm_128_32_bf<<<g3, B, 0, stream>>>(feat, W3, sup3, N_NODES);
    gather32_bf<<<gHW, B, 0, stream>>>(sup3, row_ptr, csr, b3, out);
}

// Round 6
// 279.355 us; speedup vs baseline: 6.0575x; 1.0582x over previous
//
#include <hip/hip_runtime.h>
#include <math.h>

#define N_NODES 50000
#define N_EDGES 500000
#define NB_SCAN 196  // ceil(N_NODES/256)
// L1: sup1=x@W1 [N,64] (bf16), h1=sigmoid(A@sup1+b1) (bf16)
// L2: agg1=A@h1 [N,64] (f32), feat=sigmoid(agg1@W2+b2) (f32, output)
// L3: sup3=feat@W3 [N,32] (bf16), out=A@sup3+b3 (f32, output)

// ---- bf16 helpers (RNE) ----
__device__ __forceinline__ unsigned f2bf(float f) {
    unsigned u = __float_as_uint(f);
    return (u + 0x7fffu + ((u >> 16) & 1u)) >> 16;
}
__device__ __forceinline__ float bfel_lo(unsigned p) { return __uint_as_float(p << 16); }
__device__ __forceinline__ float bfel_hi(unsigned p) { return __uint_as_float(p & 0xffff0000u); }
__device__ __forceinline__ float sigf(float x) { return 1.f / (1.f + expf(-x)); }

// ---------------- GEMM kernels: 16 output cols per thread ----------------
// C_bf16[n,64] = X[n,128] @ W[128,64]; 4 chunks/row
__global__ __launch_bounds__(256) void gemm_128_64_bf(const float* __restrict__ X,
                                                      const float* __restrict__ W,
                                                      unsigned short* __restrict__ C, int n) {
    __shared__ float Wl[128 * 64];
    for (int i = threadIdx.x; i < 128 * 64; i += 256) Wl[i] = W[i];
    __syncthreads();
    int t = blockIdx.x * 256 + threadIdx.x;
    int row = t >> 2;
    int c0 = (t & 3) * 16;
    if (row >= n) return;
    const float4* xr = (const float4*)(X + (long)row * 128);
    float acc[16];
#pragma unroll
    for (int j = 0; j < 16; j++) acc[j] = 0.f;
    for (int k4 = 0; k4 < 32; k4++) {
        float4 xv = xr[k4];
        const float* w0 = &Wl[(k4 * 4 + 0) * 64 + c0];
        const float* w1 = &Wl[(k4 * 4 + 1) * 64 + c0];
        const float* w2 = &Wl[(k4 * 4 + 2) * 64 + c0];
        const float* w3 = &Wl[(k4 * 4 + 3) * 64 + c0];
#pragma unroll
        for (int j = 0; j < 16; j++)
            acc[j] += xv.x * w0[j] + xv.y * w1[j] + xv.z * w2[j] + xv.w * w3[j];
    }
    unsigned u[8];
#pragma unroll
    for (int j = 0; j < 8; j++) u[j] = f2bf(acc[2 * j]) | (f2bf(acc[2 * j + 1]) << 16);
    uint4* cr = (uint4*)(C + (long)row * 64 + c0);
    cr[0] = make_uint4(u[0], u[1], u[2], u[3]);
    cr[1] = make_uint4(u[4], u[5], u[6], u[7]);
}

// feat[n,128] = sigmoid(X[n,64] @ W[64,128] + b); 8 chunks/row
__global__ __launch_bounds__(256) void gemm_64_128_bs(const float* __restrict__ X,
                                                      const float* __restrict__ W,
                                                      const float* __restrict__ b,
                                                      float* __restrict__ C, int n) {
    __shared__ float Wl[64 * 128];
    for (int i = threadIdx.x; i < 64 * 128; i += 256) Wl[i] = W[i];
    __syncthreads();
    int t = blockIdx.x * 256 + threadIdx.x;
    int row = t >> 3;
    int c0 = (t & 7) * 16;
    if (row >= n) return;
    const float4* xr = (const float4*)(X + (long)row * 64);
    float acc[16];
#pragma unroll
    for (int j = 0; j < 16; j++) acc[j] = 0.f;
    for (int k4 = 0; k4 < 16; k4++) {
        float4 xv = xr[k4];
        const float* w0 = &Wl[(k4 * 4 + 0) * 128 + c0];
        const float* w1 = &Wl[(k4 * 4 + 1) * 128 + c0];
        const float* w2 = &Wl[(k4 * 4 + 2) * 128 + c0];
        const float* w3 = &Wl[(k4 * 4 + 3) * 128 + c0];
#pragma unroll
        for (int j = 0; j < 16; j++)
            acc[j] += xv.x * w0[j] + xv.y * w1[j] + xv.z * w2[j] + xv.w * w3[j];
    }
    float* cr = C + (long)row * 128 + c0;
    const float* bp = b + c0;
#pragma unroll
    for (int j = 0; j < 16; j++) acc[j] = sigf(acc[j] + bp[j]);
    float4* cv = (float4*)cr;
#pragma unroll
    for (int j = 0; j < 4; j++)
        cv[j] = make_float4(acc[4 * j], acc[4 * j + 1], acc[4 * j + 2], acc[4 * j + 3]);
}

// C_bf16[n,32] = X[n,128] @ W[128,32]; 2 chunks/row
__global__ __launch_bounds__(256) void gemm_128_32_bf(const float* __restrict__ X,
                                                      const float* __restrict__ W,
                                                      unsigned short* __restrict__ C, int n) {
    __shared__ float Wl[128 * 32];
    for (int i = threadIdx.x; i < 128 * 32; i += 256) Wl[i] = W[i];
    __syncthreads();
    int t = blockIdx.x * 256 + threadIdx.x;
    int row = t >> 1;
    int c0 = (t & 1) * 16;
    if (row >= n) return;
    const float4* xr = (const float4*)(X + (long)row * 128);
    float acc[16];
#pragma unroll
    for (int j = 0; j < 16; j++) acc[j] = 0.f;
    for (int k4 = 0; k4 < 32; k4++) {
        float4 xv = xr[k4];
        const float* w0 = &Wl[(k4 * 4 + 0) * 32 + c0];
        const float* w1 = &Wl[(k4 * 4 + 1) * 32 + c0];
        const float* w2 = &Wl[(k4 * 4 + 2) * 32 + c0];
        const float* w3 = &Wl[(k4 * 4 + 3) * 32 + c0];
#pragma unroll
        for (int j = 0; j < 16; j++)
            acc[j] += xv.x * w0[j] + xv.y * w1[j] + xv.z * w2[j] + xv.w * w3[j];
    }
    unsigned u[8];
#pragma unroll
    for (int j = 0; j < 8; j++) u[j] = f2bf(acc[2 * j]) | (f2bf(acc[2 * j + 1]) << 16);
    uint4* cr = (uint4*)(C + (long)row * 32 + c0);
    cr[0] = make_uint4(u[0], u[1], u[2], u[3]);
    cr[1] = make_uint4(u[4], u[5], u[6], u[7]);
}

// ---------------- CSR build (by dst), rebuilt every launch ----------------
__global__ __launch_bounds__(256) void zero_deg(int* __restrict__ deg) {
    int i = blockIdx.x * 256 + threadIdx.x;
    if (i < N_NODES) deg[i] = 0;
}

__global__ __launch_bounds__(256) void hist_k(const int* __restrict__ dst, int* __restrict__ deg) {
    int e = blockIdx.x * 256 + threadIdx.x;
    if (e < N_EDGES) atomicAdd(&deg[dst[e]], 1);
}

__global__ __launch_bounds__(256) void block_sum_k(const int* __restrict__ deg,
                                                   int* __restrict__ bsums) {
    __shared__ int red[256];
    int i = blockIdx.x * 256 + threadIdx.x;
    red[threadIdx.x] = (i < N_NODES) ? deg[i] : 0;
    __syncthreads();
    for (int s = 128; s > 0; s >>= 1) {
        if (threadIdx.x < s) red[threadIdx.x] += red[threadIdx.x + s];
        __syncthreads();
    }
    if (threadIdx.x == 0) bsums[blockIdx.x] = red[0];
}

__global__ __launch_bounds__(256) void scan_bsums_k(int* __restrict__ bsums) {
    __shared__ int s[256];
    int t = threadIdx.x;
    s[t] = (t < NB_SCAN) ? bsums[t] : 0;
    __syncthreads();
    for (int off = 1; off < 256; off <<= 1) {
        int v = (t >= off) ? s[t - off] : 0;
        __syncthreads();
        s[t] += v;
        __syncthreads();
    }
    if (t < NB_SCAN) bsums[t] = (t == 0) ? 0 : s[t - 1];
}

__global__ __launch_bounds__(256) void rowptr_k(const int* __restrict__ deg,
                                                const int* __restrict__ bsums,
                                                int* __restrict__ row_ptr,
                                                int* __restrict__ cursor) {
    __shared__ int s[256];
    int i = blockIdx.x * 256 + threadIdx.x;
    int t = threadIdx.x;
    int d = (i < N_NODES) ? deg[i] : 0;
    s[t] = d;
    __syncthreads();
    for (int off = 1; off < 256; off <<= 1) {
        int v = (t >= off) ? s[t - off] : 0;
        __syncthreads();
        s[t] += v;
        __syncthreads();
    }
    int excl = s[t] - d + bsums[blockIdx.x];
    if (i < N_NODES) {
        row_ptr[i] = excl;
        cursor[i] = excl;
        if (i == N_NODES - 1) row_ptr[N_NODES] = excl + d;
    }
}

__global__ __launch_bounds__(256) void reorder_k(const int* __restrict__ src,
                                                 const int* __restrict__ dst,
                                                 const float* __restrict__ w,
                                                 int* __restrict__ cursor,
                                                 int2* __restrict__ csr) {
    int e = blockIdx.x * 256 + threadIdx.x;
    if (e >= N_EDGES) return;
    int pos = atomicAdd(&cursor[dst[e]], 1);
    csr[pos] = make_int2(src[e], __float_as_int(w[e]));
}

// ---------------- gather aggregation ----------------
// F=64: 32 lanes per node, each lane owns 2 features (ushort2 loads).
// Two independent edge chains per wave -> better MLP; unroll-4 -> 8 loads in flight.
__global__ __launch_bounds__(256) void gather64_sig_bf(const unsigned short* __restrict__ sup,
                                                       const int* __restrict__ row_ptr,
                                                       const int2* __restrict__ csr,
                                                       const float* __restrict__ b,
                                                       unsigned short* __restrict__ h) {
    int t = blockIdx.x * 256 + threadIdx.x;
    int node = t >> 5;
    int lane = t & 31;  // features 2*lane, 2*lane+1
    if (node >= N_NODES) return;
    int rs = row_ptr[node], re = row_ptr[node + 1];
    float acc0 = 0.f, acc1 = 0.f;
    int k = rs;
    for (; k + 4 <= re; k += 4) {
        int2 e0 = csr[k], e1 = csr[k + 1], e2 = csr[k + 2], e3 = csr[k + 3];
        unsigned p0 = *(const unsigned*)(sup + (long)e0.x * 64 + 2 * lane);
        unsigned p1 = *(const unsigned*)(sup + (long)e1.x * 64 + 2 * lane);
        unsigned p2 = *(const unsigned*)(sup + (long)e2.x * 64 + 2 * lane);
        unsigned p3 = *(const unsigned*)(sup + (long)e3.x * 64 + 2 * lane);
        float w0 = __int_as_float(e0.y), w1 = __int_as_float(e1.y);
        float w2 = __int_as_float(e2.y), w3 = __int_as_float(e3.y);
        acc0 += bfel_lo(p0) * w0 + bfel_lo(p1) * w1 + bfel_lo(p2) * w2 + bfel_lo(p3) * w3;
        acc1 += bfel_hi(p0) * w0 + bfel_hi(p1) * w1 + bfel_hi(p2) * w2 + bfel_hi(p3) * w3;
    }
    for (; k < re; k++) {
        int2 e0 = csr[k];
        unsigned p0 = *(const unsigned*)(sup + (long)e0.x * 64 + 2 * lane);
        float w0 = __int_as_float(e0.y);
        acc0 += bfel_lo(p0) * w0;
        acc1 += bfel_hi(p0) * w0;
    }
    float2 bv = ((const float2*)b)[lane];
    unsigned o = f2bf(sigf(acc0 + bv.x)) | (f2bf(sigf(acc1 + bv.y)) << 16);
    *(unsigned*)(h + (long)node * 64 + 2 * lane) = o;
}

__global__ __launch_bounds__(256) void gather64_plain_bf(const unsigned short* __restrict__ sup,
                                                         const int* __restrict__ row_ptr,
                                                         const int2* __restrict__ csr,
                                                         float* __restrict__ aggout) {
    int t = blockIdx.x * 256 + threadIdx.x;
    int node = t >> 5;
    int lane = t & 31;
    if (node >= N_NODES) return;
    int rs = row_ptr[node], re = row_ptr[node + 1];
    float acc0 = 0.f, acc1 = 0.f;
    int k = rs;
    for (; k + 4 <= re; k += 4) {
        int2 e0 = csr[k], e1 = csr[k + 1], e2 = csr[k + 2], e3 = csr[k + 3];
        unsigned p0 = *(const unsigned*)(sup + (long)e0.x * 64 + 2 * lane);
        unsigned p1 = *(const unsigned*)(sup + (long)e1.x * 64 + 2 * lane);
        unsigned p2 = *(const unsigned*)(sup + (long)e2.x * 64 + 2 * lane);
        unsigned p3 = *(const unsigned*)(sup + (long)e3.x * 64 + 2 * lane);
        float w0 = __int_as_float(e0.y), w1 = __int_as_float(e1.y);
        float w2 = __int_as_float(e2.y), w3 = __int_as_float(e3.y);
        acc0 += bfel_lo(p0) * w0 + bfel_lo(p1) * w1 + bfel_lo(p2) * w2 + bfel_lo(p3) * w3;
        acc1 += bfel_hi(p0) * w0 + bfel_hi(p1) * w1 + bfel_hi(p2) * w2 + bfel_hi(p3) * w3;
    }
    for (; k < re; k++) {
        int2 e0 = csr[k];
        unsigned p0 = *(const unsigned*)(sup + (long)e0.x * 64 + 2 * lane);
        float w0 = __int_as_float(e0.y);
        acc0 += bfel_lo(p0) * w0;
        acc1 += bfel_hi(p0) * w0;
    }
    ((float2*)(aggout + (long)node * 64))[lane] = make_float2(acc0, acc1);
}

// F=32: 16 lanes per node (4 chains/wave), ushort2 loads, float2 stores.
__global__ __launch_bounds__(256) void gather32_bf(const unsigned short* __restrict__ sup,
                                                   const int* __restrict__ row_ptr,
                                                   const int2* __restrict__ csr,
                                                   const float* __restrict__ b,
                                                   float* __restrict__ out) {
    int t = blockIdx.x * 256 + threadIdx.x;
    int node = t >> 4;
    int lane = t & 15;  // features 2*lane, 2*lane+1
    if (node >= N_NODES) return;
    int rs = row_ptr[node], re = row_ptr[node + 1];
    float acc0 = 0.f, acc1 = 0.f;
    int k = rs;
    for (; k + 4 <= re; k += 4) {
        int2 e0 = csr[k], e1 = csr[k + 1], e2 = csr[k + 2], e3 = csr[k + 3];
        unsigned p0 = *(const unsigned*)(sup + (long)e0.x * 32 + 2 * lane);
        unsigned p1 = *(const unsigned*)(sup + (long)e1.x * 32 + 2 * lane);
        unsigned p2 = *(const unsigned*)(sup + (long)e2.x * 32 + 2 * lane);
        unsigned p3 = *(const unsigned*)(sup + (long)e3.x * 32 + 2 * lane);
        float w0 = __int_as_float(e0.y), w1 = __int_as_float(e1.y);
        float w2 = __int_as_float(e2.y), w3 = __int_as_float(e3.y);
        acc0 += bfel_lo(p0) * w0 + bfel_lo(p1) * w1 + bfel_lo(p2) * w2 + bfel_lo(p3) * w3;
        acc1 += bfel_hi(p0) * w0 + bfel_hi(p1) * w1 + bfel_hi(p2) * w2 + bfel_hi(p3) * w3;
    }
    for (; k < re; k++) {
        int2 e0 = csr[k];
        unsigned p0 = *(const unsigned*)(sup + (long)e0.x * 32 + 2 * lane);
        float w0 = __int_as_float(e0.y);
        acc0 += bfel_lo(p0) * w0;
        acc1 += bfel_hi(p0) * w0;
    }
    float2 bv = ((const float2*)b)[lane];
    ((float2*)(out + (long)node * 32))[lane] = make_float2(acc0 + bv.x, acc1 + bv.y);
}

extern "C" void kernel_launch(void* const* d_in, const int* in_sizes, int n_in,
                              void* d_out, int out_size, void* d_ws, size_t ws_size,
                              hipStream_t stream) {
    const float* x  = (const float*)d_in[0];
    const int*   ei = (const int*)d_in[1];
    const float* ew = (const float*)d_in[2];
    const float* W1 = (const float*)d_in[3];
    const float* b1 = (const float*)d_in[4];
    const float* W2 = (const float*)d_in[5];
    const float* b2 = (const float*)d_in[6];
    const float* W3 = (const float*)d_in[7];
    const float* b3 = (const float*)d_in[8];

    const int* src = ei;            // edge_index[0]
    const int* dst = ei + N_EDGES;  // edge_index[1]

    float* out  = (float*)d_out;             // [N,32]
    float* feat = out + (long)N_NODES * 32;  // [N,128] = h2 (fp32, output)

    // workspace layout
    float*          agg1    = (float*)d_ws;                              // N*64 f32
    unsigned short* sup1    = (unsigned short*)(agg1 + (size_t)N_NODES * 64);  // N*64 bf16
    unsigned short* h1      = sup1 + (size_t)N_NODES * 64;               // N*64 bf16
    unsigned short* sup3    = h1 + (size_t)N_NODES * 64;                 // N*32 bf16
    int*            deg     = (int*)(sup3 + (size_t)N_NODES * 32);       // N ints
    int*            row_ptr = deg + N_NODES;                             // N+2 ints
    int*            cursor  = row_ptr + N_NODES + 2;                     // N ints
    int*            bsums   = cursor + N_NODES;                          // 196 ints (even)
    int2*           csr     = (int2*)(bsums + NB_SCAN);                  // E int2 (8B aligned)

    const int B = 256;
    const int gN  = (N_NODES + B - 1) / B;         // 196
    const int gE  = (N_EDGES + B - 1) / B;         // 1954
    const int gG64 = (N_NODES * 32 + B - 1) / B;   // 6250  (32 lanes/node)
    const int gG32 = (N_NODES * 16 + B - 1) / B;   // 3125  (16 lanes/node)
    const int g1  = (N_NODES * 4 + B - 1) / B;     // 782
    const int g2  = (N_NODES * 8 + B - 1) / B;     // 1563
    const int g3  = (N_NODES * 2 + B - 1) / B;     // 391

    // ---- CSR build (shared by all 3 layers) ----
    zero_deg<<<gN, B, 0, stream>>>(deg);
    hist_k<<<gE, B, 0, stream>>>(dst, deg);
    block_sum_k<<<NB_SCAN, B, 0, stream>>>(deg, bsums);
    scan_bsums_k<<<1, B, 0, stream>>>(bsums);
    rowptr_k<<<NB_SCAN, B, 0, stream>>>(deg, bsums, row_ptr, cursor);
    reorder_k<<<gE, B, 0, stream>>>(src, dst, ew, cursor, csr);

    // ---- Layer 1: sup1 = bf16(x@W1) ; h1 = bf16(sigmoid(A@sup1 + b1)) ----
    gemm_128_64_bf<<<g1, B, 0, stream>>>(x, W1, sup1, N_NODES);
    gather64_sig_bf<<<gG64, B, 0, stream>>>(sup1, row_ptr, csr, b1, h1);

    // ---- Layer 2 (re-associated): agg1 = A@h1 ; feat = sigmoid(agg1@W2 + b2) ----
    gather64_plain_bf<<<gG64, B, 0, stream>>>(h1, row_ptr, csr, agg1);
    gemm_64_128_bs<<<g2, B, 0, stream>>>(agg1, W2, b2, feat, N_NODES);

    // ---- Layer 3: sup3 = bf16(feat@W3) ; out = A@sup3 + b3 ----
    gemm_128_32_bf<<<g3, B, 0, stream>>>(feat, W3, sup3, N_NODES);
    gather32_bf<<<gG32, B, 0, stream>>>(sup3, row_ptr, csr, b3, out);
}

// Round 7
// 273.167 us; speedup vs baseline: 6.1947x; 1.0227x over previous
//
#include <hip/hip_runtime.h>
#include <math.h>

#define N_NODES 50000
#define N_EDGES 500000
// Chunked CSR: buckets = dst*8 + (src>>13); 8 chunks of 8192 src nodes so the
// active gather slice (~1 MB of bf16 rows) stays resident in each XCD's 4 MiB L2.
#define CSHIFT 13
#define NCHUNK 8
#define NBUCKET (N_NODES * NCHUNK)          // 400000
#define SCAN_B 512
#define NB_SCAN ((NBUCKET + SCAN_B - 1) / SCAN_B)  // 782
// L1: sup1=x@W1 [N,64] (bf16), h1=sigmoid(A@sup1+b1) (bf16)
// L2: agg1=A@h1 [N,64] (f32), feat=sigmoid(agg1@W2+b2) (f32, output)
// L3: sup3=feat@W3 [N,32] (bf16), out=A@sup3+b3 (f32, output)

// ---- bf16 helpers (RNE) ----
__device__ __forceinline__ unsigned f2bf(float f) {
    unsigned u = __float_as_uint(f);
    return (u + 0x7fffu + ((u >> 16) & 1u)) >> 16;
}
__device__ __forceinline__ float bfel_lo(unsigned p) { return __uint_as_float(p << 16); }
__device__ __forceinline__ float bfel_hi(unsigned p) { return __uint_as_float(p & 0xffff0000u); }
__device__ __forceinline__ float sigf(float x) { return 1.f / (1.f + expf(-x)); }

// ---------------- GEMM kernels: 16 output cols per thread ----------------
__global__ __launch_bounds__(256) void gemm_128_64_bf(const float* __restrict__ X,
                                                      const float* __restrict__ W,
                                                      unsigned short* __restrict__ C, int n) {
    __shared__ float Wl[128 * 64];
    for (int i = threadIdx.x; i < 128 * 64; i += 256) Wl[i] = W[i];
    __syncthreads();
    int t = blockIdx.x * 256 + threadIdx.x;
    int row = t >> 2;
    int c0 = (t & 3) * 16;
    if (row >= n) return;
    const float4* xr = (const float4*)(X + (long)row * 128);
    float acc[16];
#pragma unroll
    for (int j = 0; j < 16; j++) acc[j] = 0.f;
    for (int k4 = 0; k4 < 32; k4++) {
        float4 xv = xr[k4];
        const float* w0 = &Wl[(k4 * 4 + 0) * 64 + c0];
        const float* w1 = &Wl[(k4 * 4 + 1) * 64 + c0];
        const float* w2 = &Wl[(k4 * 4 + 2) * 64 + c0];
        const float* w3 = &Wl[(k4 * 4 + 3) * 64 + c0];
#pragma unroll
        for (int j = 0; j < 16; j++)
            acc[j] += xv.x * w0[j] + xv.y * w1[j] + xv.z * w2[j] + xv.w * w3[j];
    }
    unsigned u[8];
#pragma unroll
    for (int j = 0; j < 8; j++) u[j] = f2bf(acc[2 * j]) | (f2bf(acc[2 * j + 1]) << 16);
    uint4* cr = (uint4*)(C + (long)row * 64 + c0);
    cr[0] = make_uint4(u[0], u[1], u[2], u[3]);
    cr[1] = make_uint4(u[4], u[5], u[6], u[7]);
}

__global__ __launch_bounds__(256) void gemm_64_128_bs(const float* __restrict__ X,
                                                      const float* __restrict__ W,
                                                      const float* __restrict__ b,
                                                      float* __restrict__ C, int n) {
    __shared__ float Wl[64 * 128];
    for (int i = threadIdx.x; i < 64 * 128; i += 256) Wl[i] = W[i];
    __syncthreads();
    int t = blockIdx.x * 256 + threadIdx.x;
    int row = t >> 3;
    int c0 = (t & 7) * 16;
    if (row >= n) return;
    const float4* xr = (const float4*)(X + (long)row * 64);
    float acc[16];
#pragma unroll
    for (int j = 0; j < 16; j++) acc[j] = 0.f;
    for (int k4 = 0; k4 < 16; k4++) {
        float4 xv = xr[k4];
        const float* w0 = &Wl[(k4 * 4 + 0) * 128 + c0];
        const float* w1 = &Wl[(k4 * 4 + 1) * 128 + c0];
        const float* w2 = &Wl[(k4 * 4 + 2) * 128 + c0];
        const float* w3 = &Wl[(k4 * 4 + 3) * 128 + c0];
#pragma unroll
        for (int j = 0; j < 16; j++)
            acc[j] += xv.x * w0[j] + xv.y * w1[j] + xv.z * w2[j] + xv.w * w3[j];
    }
    float* cr = C + (long)row * 128 + c0;
    const float* bp = b + c0;
#pragma unroll
    for (int j = 0; j < 16; j++) acc[j] = sigf(acc[j] + bp[j]);
    float4* cv = (float4*)cr;
#pragma unroll
    for (int j = 0; j < 4; j++)
        cv[j] = make_float4(acc[4 * j], acc[4 * j + 1], acc[4 * j + 2], acc[4 * j + 3]);
}

__global__ __launch_bounds__(256) void gemm_128_32_bf(const float* __restrict__ X,
                                                      const float* __restrict__ W,
                                                      unsigned short* __restrict__ C, int n) {
    __shared__ float Wl[128 * 32];
    for (int i = threadIdx.x; i < 128 * 32; i += 256) Wl[i] = W[i];
    __syncthreads();
    int t = blockIdx.x * 256 + threadIdx.x;
    int row = t >> 1;
    int c0 = (t & 1) * 16;
    if (row >= n) return;
    const float4* xr = (const float4*)(X + (long)row * 128);
    float acc[16];
#pragma unroll
    for (int j = 0; j < 16; j++) acc[j] = 0.f;
    for (int k4 = 0; k4 < 32; k4++) {
        float4 xv = xr[k4];
        const float* w0 = &Wl[(k4 * 4 + 0) * 32 + c0];
        const float* w1 = &Wl[(k4 * 4 + 1) * 32 + c0];
        const float* w2 = &Wl[(k4 * 4 + 2) * 32 + c0];
        const float* w3 = &Wl[(k4 * 4 + 3) * 32 + c0];
#pragma unroll
        for (int j = 0; j < 16; j++)
            acc[j] += xv.x * w0[j] + xv.y * w1[j] + xv.z * w2[j] + xv.w * w3[j];
    }
    unsigned u[8];
#pragma unroll
    for (int j = 0; j < 8; j++) u[j] = f2bf(acc[2 * j]) | (f2bf(acc[2 * j + 1]) << 16);
    uint4* cr = (uint4*)(C + (long)row * 32 + c0);
    cr[0] = make_uint4(u[0], u[1], u[2], u[3]);
    cr[1] = make_uint4(u[4], u[5], u[6], u[7]);
}

// ---------------- chunked CSR build (by dst*8+srcchunk), rebuilt every launch ----------------
__global__ __launch_bounds__(256) void zero_deg(int* __restrict__ deg) {
    int i = blockIdx.x * 256 + threadIdx.x;
    if (i < NBUCKET) deg[i] = 0;
}

__global__ __launch_bounds__(256) void hist_k(const int* __restrict__ src,
                                              const int* __restrict__ dst,
                                              int* __restrict__ deg) {
    int e = blockIdx.x * 256 + threadIdx.x;
    if (e < N_EDGES) {
        int bkt = (dst[e] << 3) | (src[e] >> CSHIFT);
        atomicAdd(&deg[bkt], 1);
    }
}

__global__ __launch_bounds__(SCAN_B) void block_sum_k(const int* __restrict__ deg,
                                                      int* __restrict__ bsums) {
    __shared__ int red[SCAN_B];
    int i = blockIdx.x * SCAN_B + threadIdx.x;
    red[threadIdx.x] = (i < NBUCKET) ? deg[i] : 0;
    __syncthreads();
    for (int s = SCAN_B / 2; s > 0; s >>= 1) {
        if (threadIdx.x < s) red[threadIdx.x] += red[threadIdx.x + s];
        __syncthreads();
    }
    if (threadIdx.x == 0) bsums[blockIdx.x] = red[0];
}

__global__ __launch_bounds__(1024) void scan_bsums_k(int* __restrict__ bsums) {
    __shared__ int s[1024];
    int t = threadIdx.x;
    s[t] = (t < NB_SCAN) ? bsums[t] : 0;
    __syncthreads();
    for (int off = 1; off < 1024; off <<= 1) {
        int v = (t >= off) ? s[t - off] : 0;
        __syncthreads();
        s[t] += v;
        __syncthreads();
    }
    if (t < NB_SCAN) bsums[t] = (t == 0) ? 0 : s[t - 1];
}

__global__ __launch_bounds__(SCAN_B) void rowptr_k(const int* __restrict__ deg,
                                                   const int* __restrict__ bsums,
                                                   int* __restrict__ row_ptr,
                                                   int* __restrict__ cursor) {
    __shared__ int s[SCAN_B];
    int i = blockIdx.x * SCAN_B + threadIdx.x;
    int t = threadIdx.x;
    int d = (i < NBUCKET) ? deg[i] : 0;
    s[t] = d;
    __syncthreads();
    for (int off = 1; off < SCAN_B; off <<= 1) {
        int v = (t >= off) ? s[t - off] : 0;
        __syncthreads();
        s[t] += v;
        __syncthreads();
    }
    int excl = s[t] - d + bsums[blockIdx.x];
    if (i < NBUCKET) {
        row_ptr[i] = excl;
        cursor[i] = excl;
        if (i == NBUCKET - 1) row_ptr[NBUCKET] = excl + d;
    }
}

__global__ __launch_bounds__(256) void reorder_k(const int* __restrict__ src,
                                                 const int* __restrict__ dst,
                                                 const float* __restrict__ w,
                                                 int* __restrict__ cursor,
                                                 int2* __restrict__ csr) {
    int e = blockIdx.x * 256 + threadIdx.x;
    if (e >= N_EDGES) return;
    int s = src[e];
    int bkt = (dst[e] << 3) | (s >> CSHIFT);
    int pos = atomicAdd(&cursor[bkt], 1);
    csr[pos] = make_int2(s, __float_as_int(w[e]));
}

// ---------------- gather aggregation ----------------
// Node's edges are contiguous at [row_ptr[8n], row_ptr[8n+8]) and sorted by src
// chunk, so co-resident waves stream the same ~1 MB src slice (L2-resident).
__global__ __launch_bounds__(256) void gather64_sig_bf(const unsigned short* __restrict__ sup,
                                                       const int* __restrict__ row_ptr,
                                                       const int2* __restrict__ csr,
                                                       const float* __restrict__ b,
                                                       unsigned short* __restrict__ h) {
    int t = blockIdx.x * 256 + threadIdx.x;
    int node = t >> 5;
    int lane = t & 31;  // features 2*lane, 2*lane+1
    if (node >= N_NODES) return;
    int rs = row_ptr[node << 3], re = row_ptr[(node << 3) + 8];
    float acc0 = 0.f, acc1 = 0.f;
    int k = rs;
    for (; k + 4 <= re; k += 4) {
        int2 e0 = csr[k], e1 = csr[k + 1], e2 = csr[k + 2], e3 = csr[k + 3];
        unsigned p0 = *(const unsigned*)(sup + (long)e0.x * 64 + 2 * lane);
        unsigned p1 = *(const unsigned*)(sup + (long)e1.x * 64 + 2 * lane);
        unsigned p2 = *(const unsigned*)(sup + (long)e2.x * 64 + 2 * lane);
        unsigned p3 = *(const unsigned*)(sup + (long)e3.x * 64 + 2 * lane);
        float w0 = __int_as_float(e0.y), w1 = __int_as_float(e1.y);
        float w2 = __int_as_float(e2.y), w3 = __int_as_float(e3.y);
        acc0 += bfel_lo(p0) * w0 + bfel_lo(p1) * w1 + bfel_lo(p2) * w2 + bfel_lo(p3) * w3;
        acc1 += bfel_hi(p0) * w0 + bfel_hi(p1) * w1 + bfel_hi(p2) * w2 + bfel_hi(p3) * w3;
    }
    for (; k < re; k++) {
        int2 e0 = csr[k];
        unsigned p0 = *(const unsigned*)(sup + (long)e0.x * 64 + 2 * lane);
        float w0 = __int_as_float(e0.y);
        acc0 += bfel_lo(p0) * w0;
        acc1 += bfel_hi(p0) * w0;
    }
    float2 bv = ((const float2*)b)[lane];
    unsigned o = f2bf(sigf(acc0 + bv.x)) | (f2bf(sigf(acc1 + bv.y)) << 16);
    *(unsigned*)(h + (long)node * 64 + 2 * lane) = o;
}

__global__ __launch_bounds__(256) void gather64_plain_bf(const unsigned short* __restrict__ sup,
                                                         const int* __restrict__ row_ptr,
                                                         const int2* __restrict__ csr,
                                                         float* __restrict__ aggout) {
    int t = blockIdx.x * 256 + threadIdx.x;
    int node = t >> 5;
    int lane = t & 31;
    if (node >= N_NODES) return;
    int rs = row_ptr[node << 3], re = row_ptr[(node << 3) + 8];
    float acc0 = 0.f, acc1 = 0.f;
    int k = rs;
    for (; k + 4 <= re; k += 4) {
        int2 e0 = csr[k], e1 = csr[k + 1], e2 = csr[k + 2], e3 = csr[k + 3];
        unsigned p0 = *(const unsigned*)(sup + (long)e0.x * 64 + 2 * lane);
        unsigned p1 = *(const unsigned*)(sup + (long)e1.x * 64 + 2 * lane);
        unsigned p2 = *(const unsigned*)(sup + (long)e2.x * 64 + 2 * lane);
        unsigned p3 = *(const unsigned*)(sup + (long)e3.x * 64 + 2 * lane);
        float w0 = __int_as_float(e0.y), w1 = __int_as_float(e1.y);
        float w2 = __int_as_float(e2.y), w3 = __int_as_float(e3.y);
        acc0 += bfel_lo(p0) * w0 + bfel_lo(p1) * w1 + bfel_lo(p2) * w2 + bfel_lo(p3) * w3;
        acc1 += bfel_hi(p0) * w0 + bfel_hi(p1) * w1 + bfel_hi(p2) * w2 + bfel_hi(p3) * w3;
    }
    for (; k < re; k++) {
        int2 e0 = csr[k];
        unsigned p0 = *(const unsigned*)(sup + (long)e0.x * 64 + 2 * lane);
        float w0 = __int_as_float(e0.y);
        acc0 += bfel_lo(p0) * w0;
        acc1 += bfel_hi(p0) * w0;
    }
    ((float2*)(aggout + (long)node * 64))[lane] = make_float2(acc0, acc1);
}

__global__ __launch_bounds__(256) void gather32_bf(const unsigned short* __restrict__ sup,
                                                   const int* __restrict__ row_ptr,
                                                   const int2* __restrict__ csr,
                                                   const float* __restrict__ b,
                                                   float* __restrict__ out) {
    int t = blockIdx.x * 256 + threadIdx.x;
    int node = t >> 4;
    int lane = t & 15;  // features 2*lane, 2*lane+1
    if (node >= N_NODES) return;
    int rs = row_ptr[node << 3], re = row_ptr[(node << 3) + 8];
    float acc0 = 0.f, acc1 = 0.f;
    int k = rs;
    for (; k + 4 <= re; k += 4) {
        int2 e0 = csr[k], e1 = csr[k + 1], e2 = csr[k + 2], e3 = csr[k + 3];
        unsigned p0 = *(const unsigned*)(sup + (long)e0.x * 32 + 2 * lane);
        unsigned p1 = *(const unsigned*)(sup + (long)e1.x * 32 + 2 * lane);
        unsigned p2 = *(const unsigned*)(sup + (long)e2.x * 32 + 2 * lane);
        unsigned p3 = *(const unsigned*)(sup + (long)e3.x * 32 + 2 * lane);
        float w0 = __int_as_float(e0.y), w1 = __int_as_float(e1.y);
        float w2 = __int_as_float(e2.y), w3 = __int_as_float(e3.y);
        acc0 += bfel_lo(p0) * w0 + bfel_lo(p1) * w1 + bfel_lo(p2) * w2 + bfel_lo(p3) * w3;
        acc1 += bfel_hi(p0) * w0 + bfel_hi(p1) * w1 + bfel_hi(p2) * w2 + bfel_hi(p3) * w3;
    }
    for (; k < re; k++) {
        int2 e0 = csr[k];
        unsigned p0 = *(const unsigned*)(sup + (long)e0.x * 32 + 2 * lane);
        float w0 = __int_as_float(e0.y);
        acc0 += bfel_lo(p0) * w0;
        acc1 += bfel_hi(p0) * w0;
    }
    float2 bv = ((const float2*)b)[lane];
    ((float2*)(out + (long)node * 32))[lane] = make_float2(acc0 + bv.x, acc1 + bv.y);
}

extern "C" void kernel_launch(void* const* d_in, const int* in_sizes, int n_in,
                              void* d_out, int out_size, void* d_ws, size_t ws_size,
                              hipStream_t stream) {
    const float* x  = (const float*)d_in[0];
    const int*   ei = (const int*)d_in[1];
    const float* ew = (const float*)d_in[2];
    const float* W1 = (const float*)d_in[3];
    const float* b1 = (const float*)d_in[4];
    const float* W2 = (const float*)d_in[5];
    const float* b2 = (const float*)d_in[6];
    const float* W3 = (const float*)d_in[7];
    const float* b3 = (const float*)d_in[8];

    const int* src = ei;            // edge_index[0]
    const int* dst = ei + N_EDGES;  // edge_index[1]

    float* out  = (float*)d_out;             // [N,32]
    float* feat = out + (long)N_NODES * 32;  // [N,128] = h2 (fp32, output)

    // workspace layout
    float*          agg1    = (float*)d_ws;                              // N*64 f32
    unsigned short* sup1    = (unsigned short*)(agg1 + (size_t)N_NODES * 64);  // N*64 bf16
    unsigned short* h1      = sup1 + (size_t)N_NODES * 64;               // N*64 bf16
    unsigned short* sup3    = h1 + (size_t)N_NODES * 64;                 // N*32 bf16
    int*            deg     = (int*)(sup3 + (size_t)N_NODES * 32);       // NBUCKET ints
    int*            row_ptr = deg + NBUCKET;                             // NBUCKET+2 ints
    int*            cursor  = row_ptr + NBUCKET + 2;                     // NBUCKET ints
    int*            bsums   = cursor + NBUCKET;                          // NB_SCAN ints (even)
    int2*           csr     = (int2*)(bsums + NB_SCAN);                  // E int2 (8B aligned)

    const int B = 256;
    const int gB  = (NBUCKET + B - 1) / B;         // 1563 (zero buckets)
    const int gE  = (N_EDGES + B - 1) / B;         // 1954
    const int gG64 = (N_NODES * 32 + B - 1) / B;   // 6250  (32 lanes/node)
    const int gG32 = (N_NODES * 16 + B - 1) / B;   // 3125  (16 lanes/node)
    const int g1  = (N_NODES * 4 + B - 1) / B;     // 782
    const int g2  = (N_NODES * 8 + B - 1) / B;     // 1563
    const int g3  = (N_NODES * 2 + B - 1) / B;     // 391

    // ---- chunked CSR build (shared by all 3 layers) ----
    zero_deg<<<gB, B, 0, stream>>>(deg);
    hist_k<<<gE, B, 0, stream>>>(src, dst, deg);
    block_sum_k<<<NB_SCAN, SCAN_B, 0, stream>>>(deg, bsums);
    scan_bsums_k<<<1, 1024, 0, stream>>>(bsums);
    rowptr_k<<<NB_SCAN, SCAN_B, 0, stream>>>(deg, bsums, row_ptr, cursor);
    reorder_k<<<gE, B, 0, stream>>>(src, dst, ew, cursor, csr);

    // ---- Layer 1: sup1 = bf16(x@W1) ; h1 = bf16(sigmoid(A@sup1 + b1)) ----
    gemm_128_64_bf<<<g1, B, 0, stream>>>(x, W1, sup1, N_NODES);
    gather64_sig_bf<<<gG64, B, 0, stream>>>(sup1, row_ptr, csr, b1, h1);

    // ---- Layer 2 (re-associated): agg1 = A@h1 ; feat = sigmoid(agg1@W2 + b2) ----
    gather64_plain_bf<<<gG64, B, 0, stream>>>(h1, row_ptr, csr, agg1);
    gemm_64_128_bs<<<g2, B, 0, stream>>>(agg1, W2, b2, feat, N_NODES);

    // ---- Layer 3: sup3 = bf16(feat@W3) ; out = A@sup3 + b3 ----
    gemm_128_32_bf<<<g3, B, 0, stream>>>(feat, W3, sup3, N_NODES);
    gather32_bf<<<gG32, B, 0, stream>>>(sup3, row_ptr, csr, b3, out);
}